// Round 6
// baseline (384.212 us; speedup 1.0000x reference)
//
#include <hip/hip_runtime.h>
#include <hip/hip_bf16.h>
#include <hip/hip_fp16.h>
#include <stdint.h>
#include <math.h>

// ---------------------------------------------------------------------------
// AttentionLayer: Q=XWq+bq, K=XWk+bk, V=XWv+bv; O = softmax(QK^T) V
// B=4, N=2048, D=1024. fp32 I/O; internals fp16, accumulation fp32.
// R12: 256x256 read-ahead core (2x MFMA per ~3300cyc K-tile scaffold).
// 8 waves 2Mx4N, wave tile 128x64. Per 2-K-tile iter, 8 phases x 16 MFMA;
// fragment groups (A: g0={m0,1,4,5}, g1={m2,3,6,7}; B: h0={n0,1}, h1={n2,3})
// read one phase ahead into closed reg-set cycle aF/aG/bF/bG. Stage slots
// ph1..ph8 = cB0,cB1,cA0,cA1,dB0,dB1,dA0,dA1; gates vmcnt 6@ph2,10@ph5,
// 6@ph6,8@ph8 (ledger closed; prologue stages t0+t1, vmcnt(8), pre-reads).
// Deployed where grids pack exactly: QK-projection (8x32=256=1 round),
// QK^T attention (8,8,4 = 256 = 1 round). V-projection split onto the
// proven RA-128 core (8x32=256=1 round). pv_ra/prep unchanged.
// ---------------------------------------------------------------------------

typedef unsigned short ushort_t;
typedef __attribute__((ext_vector_type(8))) _Float16  f16x8;
typedef __attribute__((ext_vector_type(4))) _Float16  f16x4;
typedef __attribute__((ext_vector_type(4))) float     f32x4;

__device__ __forceinline__ void async_load16(const void* g, void* l) {
  __builtin_amdgcn_global_load_lds(
      (const __attribute__((address_space(1))) void*)g,
      (__attribute__((address_space(3))) void*)l, 16, 0, 0);
}

#define BARR do { __builtin_amdgcn_sched_barrier(0); \
                  __builtin_amdgcn_s_barrier();      \
                  __builtin_amdgcn_sched_barrier(0); } while (0)

// Stage one half (128 rows, bit5-split) of a 256-row x 64-col region: 2 insts.
// Pre-swizzled global source chunk; per-lane LDS addr == base + lane*16B.
__device__ __forceinline__ void stage_h256(const ushort_t* __restrict__ gb, long ldk,
                                           int k0, int q, ushort_t* lt, int t)
{
#pragma unroll
  for (int j = 0; j < 2; ++j) {
    const int i   = j * 64 + (t >> 3);                     // 0..127
    const int row = ((i >> 5) << 6) | (q << 5) | (i & 31); // 0..255, bit5==q
    const int ch  = (t & 7) ^ (row & 7);
    async_load16(gb + (long)row * ldk + k0 + ch * 8, lt + row * 64 + (t & 7) * 8);
  }
}

// Stage one half (64 rows, bit5-split) of a 128-row region: 1 inst.
__device__ __forceinline__ void stage_h128(const ushort_t* __restrict__ gb, long ldk,
                                           int k0, int q, ushort_t* lt, int t)
{
  const int i   = t >> 3;                                  // 0..63
  const int row = ((i >> 5) << 6) | (q << 5) | (i & 31);   // 0..127, bit5==q
  const int ch  = (t & 7) ^ (row & 7);
  async_load16(gb + (long)row * ldk + k0 + ch * 8, lt + row * 64 + (t & 7) * 8);
}

// ===========================================================================
// 256x256 RA core. LDS (ushort units): QA0 @0, QB0 @16384, QA1 @32768,
// QB1 @49152; 65536 ushorts = 128 KB. arow_l = wr*128+(lane&15), wr=wave>>2;
// brow_l = wc*64+(lane&15), wc=wave&3. row&7 == lane&7 for all frag rows.
// ===========================================================================
#define QA0 0
#define QB0 16384
#define QA1 32768
#define QB1 49152

// A-group G: m in {2G, 2G+1, 2G+4, 2G+5} (rows bit5 == G). 8 x ds_read_b128.
#define RD_AG(SET, BASE, G)                                                   \
  do { _Pragma("unroll") for (int mi_ = 0; mi_ < 4; ++mi_) {                  \
    const int r_ = arow_l + (2*(G) + (mi_ & 1) + 4*(mi_ >> 1)) * 16;          \
    SET[mi_][0] = *(const f16x8*)&lds[(BASE) + r_ * 64 + ck0];                \
    SET[mi_][1] = *(const f16x8*)&lds[(BASE) + r_ * 64 + ck1];                \
  } } while (0)

// B-group H: n in {2H, 2H+1} (rows bit5 == H). 4 x ds_read_b128.
#define RD_BH(SET, BASE, H)                                                   \
  do { _Pragma("unroll") for (int ni_ = 0; ni_ < 2; ++ni_) {                  \
    const int r_ = brow_l + (2*(H) + ni_) * 16;                               \
    SET[ni_][0] = *(const f16x8*)&lds[(BASE) + r_ * 64 + ck0];                \
    SET[ni_][1] = *(const f16x8*)&lds[(BASE) + r_ * 64 + ck1];                \
  } } while (0)

// 16 MFMA: A-group G x B-group H.
#define MM16G(AS, BS, G, H)                                                   \
  do { __builtin_amdgcn_s_setprio(1);                                         \
  _Pragma("unroll") for (int kh_ = 0; kh_ < 2; ++kh_)                         \
    _Pragma("unroll") for (int mi_ = 0; mi_ < 4; ++mi_)                       \
      _Pragma("unroll") for (int ni_ = 0; ni_ < 2; ++ni_)                     \
        acc[2*(G) + (mi_ & 1) + 4*(mi_ >> 1)][2*(H) + ni_] =                  \
            __builtin_amdgcn_mfma_f32_16x16x32_f16(                           \
                AS[mi_][kh_], BS[ni_][kh_],                                   \
                acc[2*(G) + (mi_ & 1) + 4*(mi_ >> 1)][2*(H) + ni_], 0, 0, 0); \
  __builtin_amdgcn_s_setprio(0); } while (0)

// One iteration = 2 K-tiles (a=ka bufs0, b=ka+64 bufs1); stages c=ka+128
// (bufs0), d=ka+192 (bufs1). Reads one phase ahead of their MFMA.
// Entry regs: aF=a.g0, bF=a.h0. Exit: aF=c.g0, bF=c.h0.
template<bool LAST>
__device__ __forceinline__ void iterQ(const ushort_t* __restrict__ Ab,
                                      const ushort_t* __restrict__ Bb,
                                      long lda, long ldb,
                                      ushort_t* lds, f32x4 (&acc)[8][4],
                                      int ka, int t, int arow_l, int brow_l,
                                      int ck0, int ck1,
                                      f16x8 (&aF)[4][2], f16x8 (&aG)[4][2],
                                      f16x8 (&bF)[2][2], f16x8 (&bG)[2][2])
{
  const int kc = ka + 128, kd = ka + 192;

  // ph1: rd a.h1->bG | stage c.Bh0 | MM a.g0 x a.h0
  RD_BH(bG, QB0, 1);
  if constexpr (!LAST) stage_h256(Bb, ldb, kc, 0, lds + QB0, t);
  BARR; MM16G(aF, bF, 0, 0); BARR;

  // ph2: rd a.g1->aG | stage c.Bh1 | MM a.g0 x a.h1 | GATE
  RD_AG(aG, QA0, 1);
  if constexpr (!LAST) stage_h256(Bb, ldb, kc, 1, lds + QB0, t);
  BARR; MM16G(aF, bG, 0, 1);
  if constexpr (LAST) asm volatile("s_waitcnt vmcnt(2)" ::: "memory");
  else                asm volatile("s_waitcnt vmcnt(6)" ::: "memory");
  BARR;

  // ph3: rd b.g0->aF | stage c.Ah0 | MM a.g1 x a.h1
  RD_AG(aF, QA1, 0);
  if constexpr (!LAST) stage_h256(Ab, lda, kc, 0, lds + QA0, t);
  BARR; MM16G(aG, bG, 1, 1); BARR;

  // ph4: rd b.h0->bG | stage c.Ah1 | MM a.g1 x a.h0
  RD_BH(bG, QB1, 0);
  if constexpr (!LAST) stage_h256(Ab, lda, kc, 1, lds + QA0, t);
  BARR; MM16G(aG, bF, 1, 0); BARR;

  // ph5: rd b.h1->bF | stage d.Bh0 | MM b.g0 x b.h0 | GATE
  RD_BH(bF, QB1, 1);
  if constexpr (!LAST) stage_h256(Bb, ldb, kd, 0, lds + QB1, t);
  BARR; MM16G(aF, bG, 0, 0);
  if constexpr (LAST) asm volatile("s_waitcnt vmcnt(0)" ::: "memory");
  else                asm volatile("s_waitcnt vmcnt(10)" ::: "memory");
  BARR;

  // ph6: rd b.g1->aG | stage d.Bh1 | MM b.g0 x b.h1 | GATE
  RD_AG(aG, QA1, 1);
  if constexpr (!LAST) stage_h256(Bb, ldb, kd, 1, lds + QB1, t);
  BARR; MM16G(aF, bF, 0, 1);
  if constexpr (!LAST) asm volatile("s_waitcnt vmcnt(6)" ::: "memory");
  BARR;

  // ph7: rd c.g0->aF | stage d.Ah0 | MM b.g1 x b.h1
  if constexpr (!LAST) {
    RD_AG(aF, QA0, 0);
    stage_h256(Ab, lda, kd, 0, lds + QA1, t);
  }
  BARR; MM16G(aG, bF, 1, 1); BARR;

  // ph8: rd c.h0->bF | stage d.Ah1 | MM b.g1 x b.h0 | GATE
  if constexpr (!LAST) {
    RD_BH(bF, QB0, 0);
    stage_h256(Ab, lda, kd, 1, lds + QA1, t);
  }
  BARR; MM16G(aG, bG, 1, 0);
  if constexpr (!LAST) asm volatile("s_waitcnt vmcnt(8)" ::: "memory");
  BARR;
}

// Prologue: stage t0 [B0h0,B0h1,A0h0,A0h1] + t1 [B1h0,B1h1,A1h0,A1h1];
// vmcnt(8) retires t0; pre-read aF=a.g0, bF=a.h0. Entry outstanding = t1's 8.
#define PROLOGUE_Q(LDA, LDB)                                \
  do {                                                      \
    stage_h256(Bb, (LDB),  0, 0, lds + QB0, t);             \
    stage_h256(Bb, (LDB),  0, 1, lds + QB0, t);             \
    stage_h256(Ab, (LDA),  0, 0, lds + QA0, t);             \
    stage_h256(Ab, (LDA),  0, 1, lds + QA0, t);             \
    stage_h256(Bb, (LDB), 64, 0, lds + QB1, t);             \
    stage_h256(Bb, (LDB), 64, 1, lds + QB1, t);             \
    stage_h256(Ab, (LDA), 64, 0, lds + QA1, t);             \
    stage_h256(Ab, (LDA), 64, 1, lds + QA1, t);             \
    asm volatile("s_waitcnt vmcnt(8)" ::: "memory");        \
    BARR;                                                   \
    RD_AG(aF, QA0, 0);                                      \
    RD_BH(bF, QB0, 0);                                      \
    BARR;                                                   \
  } while (0)

#define GEMM_Q(LDA, LDB)                                                      \
  do {                                                                        \
    PROLOGUE_Q(LDA, LDB);                                                     \
    _Pragma("unroll 1")                                                       \
    for (int it = 0; it < 7; ++it)                                            \
      iterQ<false>(Ab, Bb, (LDA), (LDB), lds, acc, it * 128, t,               \
                   arow_l, brow_l, ck0, ck1, aF, aG, bF, bG);                 \
    iterQ<true>(Ab, Bb, (LDA), (LDB), lds, acc, 896, t,                       \
                arow_l, brow_l, ck0, ck1, aF, aG, bF, bG);                    \
  } while (0)

// ===========================================================================
// RA-128 core (256Mx128N, proven in R11) -- used by vproj and pv.
// LDS: NA0 @0 (256x64), NB0 @16384 (128x64), NA1 @24576, NB1 @40960; 96 KB.
// ===========================================================================
#define NA0 0
#define NB0 16384
#define NA1 24576
#define NB1 40960

#define RD_A4(SET, BASE, QM)                                                  \
  do { _Pragma("unroll") for (int m_ = 0; m_ < 2; ++m_) {                     \
    SET[m_][0] = *(const f16x8*)&lds[(BASE) + (arow_l + (QM)*32 + m_*16) * 64 + ck0]; \
    SET[m_][1] = *(const f16x8*)&lds[(BASE) + (arow_l + (QM)*32 + m_*16) * 64 + ck1]; \
  } } while (0)

#define RD_B4(SET, BASE)                                                      \
  do { _Pragma("unroll") for (int q_ = 0; q_ < 2; ++q_)                       \
    _Pragma("unroll") for (int n_ = 0; n_ < 2; ++n_) {                        \
      SET[q_][n_][0] = *(const f16x8*)&lds[(BASE) + (brow_l + q_*32 + n_*16) * 64 + ck0]; \
      SET[q_][n_][1] = *(const f16x8*)&lds[(BASE) + (brow_l + q_*32 + n_*16) * 64 + ck1]; \
    } } while (0)

#define MM16(AS, BS, QM)                                                      \
  do { __builtin_amdgcn_s_setprio(1);                                         \
  _Pragma("unroll") for (int kh_ = 0; kh_ < 2; ++kh_)                         \
    _Pragma("unroll") for (int m_ = 0; m_ < 2; ++m_)                          \
      _Pragma("unroll") for (int n_ = 0; n_ < 2; ++n_) {                      \
        acc[(QM)*2+m_][n_]   = __builtin_amdgcn_mfma_f32_16x16x32_f16(        \
            AS[m_][kh_], BS[0][n_][kh_], acc[(QM)*2+m_][n_], 0, 0, 0);        \
        acc[(QM)*2+m_][2+n_] = __builtin_amdgcn_mfma_f32_16x16x32_f16(        \
            AS[m_][kh_], BS[1][n_][kh_], acc[(QM)*2+m_][2+n_], 0, 0, 0);      \
      }                                                                       \
  __builtin_amdgcn_s_setprio(0); } while (0)

#define MM16S(AS, BS, QM, SC)                                                 \
  do { __builtin_amdgcn_s_setprio(1);                                         \
  _Pragma("unroll") for (int m_ = 0; m_ < 2; ++m_)                            \
    _Pragma("unroll") for (int kh_ = 0; kh_ < 2; ++kh_) {                     \
      const f16x8 as_ = AS[m_][kh_] * (_Float16)(SC)[(QM)*2+m_];              \
      _Pragma("unroll") for (int n_ = 0; n_ < 2; ++n_) {                      \
        acc[(QM)*2+m_][n_]   = __builtin_amdgcn_mfma_f32_16x16x32_f16(        \
            as_, BS[0][n_][kh_], acc[(QM)*2+m_][n_], 0, 0, 0);                \
        acc[(QM)*2+m_][2+n_] = __builtin_amdgcn_mfma_f32_16x16x32_f16(        \
            as_, BS[1][n_][kh_], acc[(QM)*2+m_][2+n_], 0, 0, 0);              \
      } }                                                                     \
  __builtin_amdgcn_s_setprio(0); } while (0)

template<bool LAST>
__device__ __forceinline__ void iterRA(const ushort_t* __restrict__ Ab,
                                       const ushort_t* __restrict__ Bb,
                                       long lda, long ldb,
                                       ushort_t* lds, f32x4 (&acc)[4][4],
                                       int ka, int t, int arow_l, int brow_l,
                                       int ck0, int ck1,
                                       f16x8 (&aF)[2][2], f16x8 (&aG)[2][2],
                                       f16x8 (&bF)[2][2][2], f16x8 (&bG)[2][2][2])
{
  const int kc = ka + 128, kd = ka + 192;

  RD_A4(aG, NA0, 1);
  if constexpr (!LAST) { stage_h256(Ab, lda, kc, 0, lds + NA0, t);
                         stage_h128(Bb, ldb, kc, 0, lds + NB0, t); }
  BARR;
  MM16(aF, bF, 0);
  if constexpr (LAST) asm volatile("s_waitcnt vmcnt(0)" ::: "memory");
  else                asm volatile("s_waitcnt vmcnt(3)" ::: "memory");
  BARR;

  RD_A4(aF, NA1, 0);
  RD_B4(bG, NB1);
  if constexpr (!LAST) { stage_h256(Ab, lda, kc, 1, lds + NA0, t);
                         stage_h128(Bb, ldb, kc, 1, lds + NB0, t); }
  BARR;
  MM16(aG, bF, 1);
  BARR;

  RD_A4(aG, NA1, 1);
  if constexpr (!LAST) { stage_h256(Ab, lda, kd, 0, lds + NA1, t);
                         stage_h128(Bb, ldb, kd, 0, lds + NB1, t); }
  BARR;
  MM16(aF, bG, 0);
  if constexpr (!LAST) asm volatile("s_waitcnt vmcnt(3)" ::: "memory");
  BARR;

  if constexpr (!LAST) {
    RD_A4(aF, NA0, 0);
    RD_B4(bF, NB0);
    stage_h256(Ab, lda, kd, 1, lds + NA1, t);
    stage_h128(Bb, ldb, kd, 1, lds + NB1, t);
  }
  BARR;
  MM16(aG, bG, 1);
  BARR;
}

template<bool LAST>
__device__ __forceinline__ void pv_iterRA(const ushort_t* __restrict__ Ab,
                                          const ushort_t* __restrict__ Bb,
                                          ushort_t* lds, const float (*ScL)[256],
                                          f32x4 (&acc)[4][4],
                                          int ka, int t, int arow_l, int brow_l,
                                          int ck0, int ck1,
                                          f16x8 (&aF)[2][2], f16x8 (&aG)[2][2],
                                          f16x8 (&bF)[2][2][2], f16x8 (&bG)[2][2][2])
{
  const int kc = ka + 128, kd = ka + 192;
  const int cba = ka >> 6;
  float sa4[4], sb4[4];
#pragma unroll
  for (int s = 0; s < 4; ++s) {
    sa4[s] = ScL[cba][arow_l + s * 16];
    sb4[s] = ScL[cba + 1][arow_l + s * 16];
  }

  RD_A4(aG, NA0, 1);
  if constexpr (!LAST) { stage_h256(Ab, 2048, kc, 0, lds + NA0, t);
                         stage_h128(Bb, 2048, kc, 0, lds + NB0, t); }
  BARR;
  MM16S(aF, bF, 0, sa4);
  if constexpr (LAST) asm volatile("s_waitcnt vmcnt(0)" ::: "memory");
  else                asm volatile("s_waitcnt vmcnt(3)" ::: "memory");
  BARR;

  RD_A4(aF, NA1, 0);
  RD_B4(bG, NB1);
  if constexpr (!LAST) { stage_h256(Ab, 2048, kc, 1, lds + NA0, t);
                         stage_h128(Bb, 2048, kc, 1, lds + NB0, t); }
  BARR;
  MM16S(aG, bF, 1, sa4);
  BARR;

  RD_A4(aG, NA1, 1);
  if constexpr (!LAST) { stage_h256(Ab, 2048, kd, 0, lds + NA1, t);
                         stage_h128(Bb, 2048, kd, 0, lds + NB1, t); }
  BARR;
  MM16S(aF, bG, 0, sb4);
  if constexpr (!LAST) asm volatile("s_waitcnt vmcnt(3)" ::: "memory");
  BARR;

  if constexpr (!LAST) {
    RD_A4(aF, NA0, 0);
    RD_B4(bF, NB0);
    stage_h256(Ab, 2048, kd, 1, lds + NA1, t);
    stage_h128(Bb, 2048, kd, 1, lds + NB1, t);
  }
  BARR;
  MM16S(aG, bG, 1, sb4);
  BARR;
}

#define PROLOGUE_RA(LDA, LDB)                               \
  do {                                                      \
    stage_h256(Ab, (LDA),  0, 0, lds + NA0, t);             \
    stage_h128(Bb, (LDB),  0, 0, lds + NB0, t);             \
    stage_h256(Ab, (LDA),  0, 1, lds + NA0, t);             \
    stage_h128(Bb, (LDB),  0, 1, lds + NB0, t);             \
    asm volatile("s_waitcnt vmcnt(0)" ::: "memory");        \
    BARR;                                                   \
    RD_A4(aF, NA0, 0);                                      \
    RD_B4(bF, NB0);                                         \
    stage_h256(Ab, (LDA), 64, 0, lds + NA1, t);             \
    stage_h128(Bb, (LDB), 64, 0, lds + NB1, t);             \
    stage_h256(Ab, (LDA), 64, 1, lds + NA1, t);             \
    stage_h128(Bb, (LDB), 64, 1, lds + NB1, t);             \
    BARR;                                                   \
  } while (0)

// ---------------------------------------------------------------------------
// QK-projection on the 256x256 core. A = Xh [8192][1024], BT = Wt rows
// 0..2047 (Q cols | K cols). grid (8, M/256) = 256 blocks = 1 round.
// ---------------------------------------------------------------------------
__global__ __launch_bounds__(512, 2)
void qkproj_kernel(const ushort_t* __restrict__ A, const ushort_t* __restrict__ BT,
                   const float* __restrict__ bq, const float* __restrict__ bk,
                   __half* __restrict__ Qh, __half* __restrict__ Kh)
{
  __shared__ __align__(16) ushort_t lds[65536];   // 128 KB

  const int nb = gridDim.x * gridDim.y;           // %8==0
  int id = blockIdx.y * gridDim.x + blockIdx.x;
  id = (id & 7) * (nb >> 3) + (id >> 3);          // bijective XCD swizzle
  const int bx = id % gridDim.x;                  // 0..7 (N-tile of 256 over Q|K)
  const int by = id / gridDim.x;                  // M-tile of 256

  const ushort_t* Ab = A  + (long)by * 256 * 1024;
  const ushort_t* Bb = BT + (long)bx * 256 * 1024;

  const int t    = threadIdx.x;
  const int lane = t & 63;
  const int wave = t >> 6;
  const int wr   = wave >> 2;                     // 0..1 (M, 128 rows)
  const int wc   = wave & 3;                      // 0..3 (N, 64 cols)
  const int arow_l = wr * 128 + (lane & 15);
  const int brow_l = wc * 64  + (lane & 15);
  const int ck0 = (((lane >> 4)    ) ^ (lane & 7)) * 8;
  const int ck1 = ((4 + (lane >> 4)) ^ (lane & 7)) * 8;

  f32x4 acc[8][4];
  const f32x4 zero = {0.0f, 0.0f, 0.0f, 0.0f};
#pragma unroll
  for (int i = 0; i < 8; ++i)
#pragma unroll
    for (int j = 0; j < 4; ++j) acc[i][j] = zero;

  f16x8 aF[4][2], aG[4][2], bF[2][2], bG[2][2];

  GEMM_Q(1024, 1024);

  const int er = (lane >> 4) * 4, ec = lane & 15;
  const int tgt = bx >> 2;                        // 0:Q 1:K (uniform)
  const float* bias = (tgt == 0) ? bq : bk;
  __half* o = (tgt == 0) ? Qh : Kh;

#pragma unroll
  for (int ni = 0; ni < 4; ++ni) {
    const int col = (bx & 3) * 256 + wc * 64 + ni * 16 + ec;   // 0..1023
    const float bval = bias[col];
#pragma unroll
    for (int mi = 0; mi < 8; ++mi) {
      const long grow0 = (long)by * 256 + wr * 128 + mi * 16 + er;
#pragma unroll
      for (int r = 0; r < 4; ++r)
        o[(grow0 + r) * 1024 + col] = __float2half(acc[mi][ni][r] + bval);
    }
  }
}

// ---------------------------------------------------------------------------
// V-projection on the RA-128 core. BT rows 2048+bx*128. grid (8, M/256).
// ---------------------------------------------------------------------------
__global__ __launch_bounds__(512, 2)
void vproj_kernel(const ushort_t* __restrict__ A, const ushort_t* __restrict__ BT,
                  const float* __restrict__ bvp, ushort_t* __restrict__ Vt)
{
  __shared__ __align__(16) ushort_t lds[49152];   // 96 KB

  const int nb = gridDim.x * gridDim.y;           // 256, %8==0
  int id = blockIdx.y * gridDim.x + blockIdx.x;
  id = (id & 7) * (nb >> 3) + (id >> 3);
  const int bx = id % gridDim.x;                  // 0..7 (V N-tile of 128)
  const int by = id / gridDim.x;                  // M-tile of 256

  const ushort_t* Ab = A  + (long)by * 256 * 1024;
  const ushort_t* Bb = BT + (long)(16 + bx) * 128 * 1024;

  const int t    = threadIdx.x;
  const int lane = t & 63;
  const int wave = t >> 6;
  const int wr   = wave >> 1;                     // 0..3
  const int wc   = wave & 1;                      // 0..1
  const int arow_l = wr * 64 + (lane & 15);
  const int brow_l = wc * 64 + (lane & 15);
  const int ck0 = (((lane >> 4)    ) ^ (lane & 7)) * 8;
  const int ck1 = ((4 + (lane >> 4)) ^ (lane & 7)) * 8;

  f32x4 acc[4][4];
  const f32x4 zero = {0.0f, 0.0f, 0.0f, 0.0f};
#pragma unroll
  for (int i = 0; i < 4; ++i)
#pragma unroll
    for (int j = 0; j < 4; ++j) acc[i][j] = zero;

  f16x8 aF[2][2], aG[2][2], bF[2][2][2], bG[2][2][2];

  PROLOGUE_RA(1024, 1024);
#pragma unroll 1
  for (int it = 0; it < 7; ++it)
    iterRA<false>(Ab, Bb, 1024, 1024, lds, acc, it * 128, t, arow_l, brow_l,
                  ck0, ck1, aF, aG, bF, bG);
  iterRA<true>(Ab, Bb, 1024, 1024, lds, acc, 896, t, arow_l, brow_l,
               ck0, ck1, aF, aG, bF, bG);

  const int er = (lane >> 4) * 4, ec = lane & 15;
#pragma unroll
  for (int ni = 0; ni < 4; ++ni) {
    const int col = bx * 128 + wc * 64 + ni * 16 + ec;   // 0..1023
    const float bval = bvp[col];
#pragma unroll
    for (int mi = 0; mi < 4; ++mi) {
      const long grow0 = (long)by * 256 + wr * 64 + mi * 16 + er;
      const long b  = grow0 >> 11;                // batch
      const long ml = grow0 & 2047;               // aligned to 4
      f16x4 v4;
#pragma unroll
      for (int r = 0; r < 4; ++r) v4[r] = (_Float16)(acc[mi][ni][r] + bval);
      *(f16x4*)&Vt[b * 2097152 + (long)col * 2048 + ml] = v4;
    }
  }
}

// ---------------------------------------------------------------------------
// QK^T on the 256x256 core with fused partial softmax, 64-col chunks.
// Wave (wr,wc) owns 128 rows x 64 cols; chunk cc = bx*4+wc (0..31).
// grid (8, 8, 4) = 256 blocks = 1 round.
// ---------------------------------------------------------------------------
__global__ __launch_bounds__(512, 2)
void qkattn_kernel(const ushort_t* __restrict__ Q, const ushort_t* __restrict__ Kh,
                   __half* __restrict__ S, float* __restrict__ PM, float* __restrict__ PS)
{
  __shared__ __align__(16) ushort_t lds[65536];

  const int nb = gridDim.x * gridDim.y;           // 64, %8==0
  int id = blockIdx.y * gridDim.x + blockIdx.x;
  id = (id & 7) * (nb >> 3) + (id >> 3);
  const int bx = id % gridDim.x;                  // 0..7 (K-tile of 256)
  const int by = id / gridDim.x;                  // 0..7 (Q-tile of 256)
  const long z = blockIdx.z;

  const ushort_t* Ab = Q  + z * 2048 * 1024 + (long)by * 256 * 1024;
  const ushort_t* Bb = Kh + z * 2048 * 1024 + (long)bx * 256 * 1024;
  __half* Sb = S + z * 2048 * 2048;

  const int t    = threadIdx.x;
  const int lane = t & 63;
  const int wave = t >> 6;
  const int wr   = wave >> 2;
  const int wc   = wave & 3;
  const int arow_l = wr * 128 + (lane & 15);
  const int brow_l = wc * 64  + (lane & 15);
  const int ck0 = (((lane >> 4)    ) ^ (lane & 7)) * 8;
  const int ck1 = ((4 + (lane >> 4)) ^ (lane & 7)) * 8;

  f32x4 acc[8][4];
  const f32x4 zero = {0.0f, 0.0f, 0.0f, 0.0f};
#pragma unroll
  for (int i = 0; i < 8; ++i)
#pragma unroll
    for (int j = 0; j < 4; ++j) acc[i][j] = zero;

  f16x8 aF[4][2], aG[4][2], bF[2][2], bG[2][2];

  GEMM_Q(1024, 1024);

  const int er = (lane >> 4) * 4, ec = lane & 15;
  const int cc = bx * 4 + wc;                     // 0..31
  float* PMb = PM + z * 32 * 2048 + (long)cc * 2048;
  float* PSb = PS + z * 32 * 2048 + (long)cc * 2048;

#pragma unroll
  for (int mi = 0; mi < 8; ++mi)
#pragma unroll
    for (int r = 0; r < 4; ++r) {
      float m = fmaxf(fmaxf(acc[mi][0][r], acc[mi][1][r]),
                      fmaxf(acc[mi][2][r], acc[mi][3][r]));
      m = fmaxf(m, __shfl_xor(m, 1));   // reduce over the 16 ec lanes
      m = fmaxf(m, __shfl_xor(m, 2));
      m = fmaxf(m, __shfl_xor(m, 4));
      m = fmaxf(m, __shfl_xor(m, 8));
      float s = 0.0f;
#pragma unroll
      for (int ni = 0; ni < 4; ++ni) {
        const float e = __expf(acc[mi][ni][r] - m);
        acc[mi][ni][r] = e;
        s += e;
      }
      s += __shfl_xor(s, 1);
      s += __shfl_xor(s, 2);
      s += __shfl_xor(s, 4);
      s += __shfl_xor(s, 8);
      if (ec == 0) {
        const long row = (long)by * 256 + wr * 128 + mi * 16 + er + r;
        PMb[row] = m;
        PSb[row] = s;
      }
    }

  // store p_unnorm = exp(s - m_chunk) fp16
#pragma unroll
  for (int ni = 0; ni < 4; ++ni) {
    const long col = (long)bx * 256 + wc * 64 + ni * 16 + ec;
#pragma unroll
    for (int mi = 0; mi < 8; ++mi)
#pragma unroll
      for (int r = 0; r < 4; ++r) {
        const long grow = (long)by * 256 + wr * 128 + mi * 16 + er + r;
        Sb[grow * 2048 + col] = __float2half(acc[mi][ni][r]);
      }
  }
}

// ---------------------------------------------------------------------------
// PV on the RA-128 core, softmax-reduce fused into the prologue.
// grid (8, 8, 4) = 256 blocks. K = 2048.
// ---------------------------------------------------------------------------
__global__ __launch_bounds__(512, 2)
void pv_ra_kernel(const ushort_t* __restrict__ S, const ushort_t* __restrict__ Vt,
                  const float* __restrict__ PM, const float* __restrict__ PS,
                  float* __restrict__ Out)
{
  __shared__ __align__(16) ushort_t lds[49152];   // 96 KB
  __shared__ float ScL[32][256];                  // +32 KB = 128 KB

  const int nb = gridDim.x * gridDim.y;           // 64, %8==0
  int id = blockIdx.y * gridDim.x + blockIdx.x;
  id = (id & 7) * (nb >> 3) + (id >> 3);
  const int bx = id % gridDim.x;                  // N-tile (Out cols / Vt rows)
  const int by = id / gridDim.x;                  // M-tile (S rows)
  const long z = blockIdx.z;

  const ushort_t* Ab = S  + z * 4194304 + (long)by * 256 * 2048;
  const ushort_t* Bb = Vt + z * 2097152 + (long)bx * 128 * 2048;
  float* Cb = Out + z * 2048 * 1024;

  const int t = threadIdx.x;

  // ---- fused softmax reduce for this block's 256 rows ----
  if (t < 256) {
    const long row = (long)by * 256 + t;
    const float* PMb = PM + z * 32 * 2048;
    const float* PSb = PS + z * 32 * 2048;
    float pm[32];
    float m = -3.4e38f;
#pragma unroll
    for (int cb = 0; cb < 32; ++cb) {
      pm[cb] = PMb[(long)cb * 2048 + row];
      m = fmaxf(m, pm[cb]);
    }
    float l = 0.0f;
#pragma unroll
    for (int cb = 0; cb < 32; ++cb)
      l += PSb[(long)cb * 2048 + row] * __expf(pm[cb] - m);
    const float inv = 1.0f / l;
#pragma unroll
    for (int cb = 0; cb < 32; ++cb)
      ScL[cb][t] = __expf(pm[cb] - m) * inv;
  }
  __syncthreads();   // full drain; ScL visible; vmcnt clean before staging

  const int lane = t & 63;
  const int wave = t >> 6;
  const int wr   = wave >> 1;
  const int wc   = wave & 1;
  const int arow_l = wr * 64 + (lane & 15);
  const int brow_l = wc * 64 + (lane & 15);
  const int ck0 = (((lane >> 4)    ) ^ (lane & 7)) * 8;
  const int ck1 = ((4 + (lane >> 4)) ^ (lane & 7)) * 8;

  f32x4 acc[4][4];
  const f32x4 zero = {0.0f, 0.0f, 0.0f, 0.0f};
#pragma unroll
  for (int i = 0; i < 4; ++i)
#pragma unroll
    for (int j = 0; j < 4; ++j) acc[i][j] = zero;

  f16x8 aF[2][2], aG[2][2], bF[2][2][2], bG[2][2][2];

  PROLOGUE_RA(2048, 2048);
#pragma unroll 1
  for (int it = 0; it < 15; ++it)
    pv_iterRA<false>(Ab, Bb, lds, ScL, acc, it * 128, t, arow_l, brow_l,
                     ck0, ck1, aF, aG, bF, bG);
  pv_iterRA<true>(Ab, Bb, lds, ScL, acc, 1920, t, arow_l, brow_l,
                  ck0, ck1, aF, aG, bF, bG);

  const int er = (lane >> 4) * 4, ec = lane & 15;
#pragma unroll
  for (int ni = 0; ni < 4; ++ni) {
    const int gcol = bx * 128 + wc * 64 + ni * 16 + ec;
#pragma unroll
    for (int mi = 0; mi < 4; ++mi) {
#pragma unroll
      for (int r = 0; r < 4; ++r) {
        const long grow = (long)by * 256 + wr * 64 + mi * 16 + er + r;
        Cb[grow * 1024 + gcol] = acc[mi][ni][r];
      }
    }
  }
}

// ---------------------------------------------------------------------------
// Fused prep: z<3 -> weight transpose+cvt; z>=3 -> X fp32->fp16 slice.
// grid (32, 32, 7), 256 thr.
// ---------------------------------------------------------------------------
__global__ __launch_bounds__(256)
void prep_kernel(const float* __restrict__ W0, const float* __restrict__ W1,
                 const float* __restrict__ W2, __half* __restrict__ dstW,
                 const float* __restrict__ X, __half* __restrict__ Xh)
{
  __shared__ float tile[32][33];
  const int z = blockIdx.z;
  if (z < 3) {
    const float* src = (z == 0) ? W0 : (z == 1) ? W1 : W2;
    __half* d = dstW + (long)z * 1024 * 1024;
    const int c0 = blockIdx.x * 32;
    const int r0 = blockIdx.y * 32;
    const int tx = threadIdx.x & 31;
    const int ty = threadIdx.x >> 5;
#pragma unroll
    for (int i = 0; i < 32; i += 8)
      tile[ty + i][tx] = src[(long)(r0 + ty + i) * 1024 + (c0 + tx)];
    __syncthreads();
#pragma unroll
    for (int i = 0; i < 32; i += 8)
      d[(long)(c0 + ty + i) * 1024 + (r0 + tx)] = __float2half(tile[tx][ty + i]);
  } else {
    const int bid = blockIdx.y * gridDim.x + blockIdx.x;        // 0..1023
    const long i = (((long)(z - 3) * 1024 + bid) * 256 + threadIdx.x) * 8;
    const float4 a = *(const float4*)(X + i);
    const float4 b = *(const float4*)(X + i + 4);
    f16x8 h;
    h[0] = (_Float16)a.x; h[1] = (_Float16)a.y; h[2] = (_Float16)a.z; h[3] = (_Float16)a.w;
    h[4] = (_Float16)b.x; h[5] = (_Float16)b.y; h[6] = (_Float16)b.z; h[7] = (_Float16)b.w;
    *(f16x8*)((ushort_t*)Xh + i) = h;
  }
}

// ---------------------------------------------------------------------------
extern "C" void kernel_launch(void* const* d_in, const int* in_sizes, int n_in,
                              void* d_out, int out_size, void* d_ws, size_t ws_size,
                              hipStream_t stream)
{
  const int  Bb = 4, Nn = 2048, Dd = 1024;
  const long BN = (long)Bb * Nn;  // 8192

  const float* X  = (const float*)d_in[0];
  const float* Wq = (const float*)d_in[1];
  const float* bq = (const float*)d_in[2];
  const float* Wk = (const float*)d_in[3];
  const float* bk = (const float*)d_in[4];
  const float* Wv = (const float*)d_in[5];
  const float* bv = (const float*)d_in[6];
  float* Out      = (float*)d_out;

  uint8_t* w = (uint8_t*)d_ws;
  ushort_t* Wt = (ushort_t*)w;  w += (size_t)3 * Dd * Dd * 2;  // Wq^T|Wk^T|Wv^T fp16

  const size_t statsBytes = (size_t)Bb * 32 * Nn * 4;   // 1 MB each
  const size_t fullNeed = (size_t)3 * Dd * Dd * 2       // Wt
                        + 4 * ((size_t)BN * Dd * 2)     // Xh, Q, K, Vt fp16
                        + (size_t)Bb * Nn * Nn * 2      // S fp16
                        + 2 * statsBytes;               // PM, PS

  if (ws_size >= fullNeed) {
    ushort_t* Xh = (ushort_t*)w;  w += (size_t)BN * Dd * 2;
    ushort_t* Q  = (ushort_t*)w;  w += (size_t)BN * Dd * 2;
    ushort_t* Kb = (ushort_t*)w;  w += (size_t)BN * Dd * 2;
    ushort_t* Vt = (ushort_t*)w;  w += (size_t)BN * Dd * 2;  // [B][Dd][Nn]
    ushort_t* S  = (ushort_t*)w;  w += (size_t)Bb * Nn * Nn * 2;
    float*    PM = (float*)w;     w += statsBytes;
    float*    PS = (float*)w;

    prep_kernel<<<dim3(32, 32, 7), 256, 0, stream>>>(Wq, Wk, Wv, (__half*)Wt, X, (__half*)Xh);

    qkproj_kernel<<<dim3(8, BN / 256, 1), 512, 0, stream>>>(
        Xh, Wt, bq, bk, (__half*)Q, (__half*)Kb);

    vproj_kernel<<<dim3(8, BN / 256, 1), 512, 0, stream>>>(Xh, Wt, bv, Vt);

    qkattn_kernel<<<dim3(Nn / 256, Nn / 256, Bb), 512, 0, stream>>>(
        Q, Kb, (__half*)S, PM, PS);

    pv_ra_kernel<<<dim3(Dd / 128, Nn / 256, Bb), 512, 0, stream>>>(
        S, Vt, PM, PS, Out);
  } else {
    // Per-batch fallback (~32 MB ws): same cores, z-extent 1
    ushort_t* Xh = (ushort_t*)w;  w += (size_t)Nn * Dd * 2;
    ushort_t* Q  = (ushort_t*)w;  w += (size_t)Nn * Dd * 2;
    ushort_t* Kb = (ushort_t*)w;  w += (size_t)Nn * Dd * 2;
    ushort_t* Vt = (ushort_t*)w;  w += (size_t)Nn * Dd * 2;
    ushort_t* S  = (ushort_t*)w;  w += (size_t)Nn * Nn * 2;
    float*    PM = (float*)w;     w += (size_t)32 * Nn * 4;
    float*    PS = (float*)w;

    for (int b = 0; b < Bb; ++b) {
      const float* Xb = X + (long)b * Nn * Dd;
      prep_kernel<<<dim3(32, 32, b == 0 ? 4 : 1), 256, 0, stream>>>(
          Wq, Wk, Wv, (__half*)Wt, Xb, (__half*)Xh);  // z=3 slice converts Xb
      qkproj_kernel<<<dim3(8, Nn / 256, 1), 512, 0, stream>>>(
          Xh, Wt, bq, bk, (__half*)Q, (__half*)Kb);
      vproj_kernel<<<dim3(8, Nn / 256, 1), 512, 0, stream>>>(Xh, Wt, bv, Vt);
      qkattn_kernel<<<dim3(Nn / 256, Nn / 256, 1), 512, 0, stream>>>(
          Q, Kb, (__half*)S, PM, PS);
      pv_ra_kernel<<<dim3(Dd / 128, Nn / 256, 1), 512, 0, stream>>>(
          S, Vt, PM, PS, Out + (long)b * Nn * Dd);
    }
  }
}

// Round 7
// 258.730 us; speedup vs baseline: 1.4850x; 1.4850x over previous
//
#include <hip/hip_runtime.h>
#include <hip/hip_bf16.h>
#include <hip/hip_fp16.h>
#include <stdint.h>
#include <math.h>

// ---------------------------------------------------------------------------
// AttentionLayer: Q=XWq+bq, K=XWk+bk, V=XWv+bv; O = softmax(QK^T) V
// B=4, N=2048, D=1024. fp32 I/O; internals fp16, accumulation fp32.
// R13: R12's RA-256^2 core spilled (~240 live VGPR > 256 budget; WRITE_SIZE
// +54MB of scratch writes, MfmaUtil 10%). Revert to proven parts only:
//  - qkproj + qkattn on the R8 8-phase 256x256 core (same-phase reads,
//    fragments transient, VGPR=128, measured ~860 TF/round) with exactly
//    1-round grids: (8,32)=256 and (8,8,4)=256 blocks.
//  - vproj on the RA-128 core (R11/R12-proven), grid (8,32)=256.
//  - pv on RA-128 + fused softmax-reduce (R12-proven), grid (8,8,4).
//  - prep fused transpose+cvt (R10+-proven).
// ---------------------------------------------------------------------------

typedef unsigned short ushort_t;
typedef __attribute__((ext_vector_type(8))) _Float16  f16x8;
typedef __attribute__((ext_vector_type(4))) _Float16  f16x4;
typedef __attribute__((ext_vector_type(4))) float     f32x4;

__device__ __forceinline__ void async_load16(const void* g, void* l) {
  __builtin_amdgcn_global_load_lds(
      (const __attribute__((address_space(1))) void*)g,
      (__attribute__((address_space(3))) void*)l, 16, 0, 0);
}

#define BARR do { __builtin_amdgcn_sched_barrier(0); \
                  __builtin_amdgcn_s_barrier();      \
                  __builtin_amdgcn_s_barrier();      \
                  __builtin_amdgcn_sched_barrier(0); } while (0)
#undef BARR
#define BARR do { __builtin_amdgcn_sched_barrier(0); \
                  __builtin_amdgcn_s_barrier();      \
                  __builtin_amdgcn_sched_barrier(0); } while (0)

// ===========================================================================
// 256x256 8-phase core (R8-proven, same-phase reads). LDS 128 KB.
// 8 waves as 2M x 4N; wave tile 128x64; acc[8][4].
// ===========================================================================
#define A0OFF 0
#define B0OFF 16384
#define A1OFF 32768
#define B1OFF 49152

template<int SHIFT>
__device__ __forceinline__ void stage_half(const ushort_t* __restrict__ gb,
                                           int k0, int q, ushort_t* lt, int t)
{
#pragma unroll
  for (int j = 0; j < 2; ++j) {
    const int i   = j * 64 + (t >> 3);
    const int row = ((i >> SHIFT) << (SHIFT + 1)) | (q << SHIFT) | (i & ((1 << SHIFT) - 1));
    const int ch  = (t & 7) ^ (row & 7);
    async_load16(gb + (long)row * 1024 + k0 + ch * 8, lt + row * 64 + (t & 7) * 8);
  }
}

#define RD_A(TP, QM)                                                          \
  do { _Pragma("unroll") for (int m_ = 0; m_ < 4; ++m_) {                     \
    af[m_][0] = *(const f16x8*)&(TP)[(arow0 + (QM)*64 + m_*16) * 64 + ck0];   \
    af[m_][1] = *(const f16x8*)&(TP)[(arow0 + (QM)*64 + m_*16) * 64 + ck1];   \
  } } while (0)

#define RD_B(TP, QN)                                                          \
  do { _Pragma("unroll") for (int n_ = 0; n_ < 2; ++n_) {                     \
    bf[n_][0] = *(const f16x8*)&(TP)[(brow0 + (QN)*32 + n_*16) * 64 + ck0];   \
    bf[n_][1] = *(const f16x8*)&(TP)[(brow0 + (QN)*32 + n_*16) * 64 + ck1];   \
  } } while (0)

#define MM(QM, QN)                                                            \
  do { __builtin_amdgcn_s_setprio(1);                                         \
  _Pragma("unroll") for (int kh_ = 0; kh_ < 2; ++kh_)                         \
    _Pragma("unroll") for (int m_ = 0; m_ < 4; ++m_)                          \
      _Pragma("unroll") for (int n_ = 0; n_ < 2; ++n_)                        \
        acc[(QM)*4+m_][(QN)*2+n_] = __builtin_amdgcn_mfma_f32_16x16x32_f16(   \
            af[m_][kh_], bf[n_][kh_], acc[(QM)*4+m_][(QN)*2+n_], 0, 0, 0);    \
  __builtin_amdgcn_s_setprio(0); } while (0)

template<bool LAST>
__device__ __forceinline__ void iter256(const ushort_t* __restrict__ Ab,
                                        const ushort_t* __restrict__ Bb,
                                        ushort_t* lds, f32x4 (&acc)[8][4],
                                        int ka, int t, int arow0, int brow0,
                                        int ck0, int ck1)
{
  const int kb = ka + 64, kc = ka + 128, kd = ka + 192;
  f16x8 af[4][2], bf[2][2];

  RD_A(lds + A0OFF, 0); RD_B(lds + B0OFF, 0);
  stage_half<5>(Bb, kb, 0, lds + B1OFF, t);
  BARR; MM(0, 0); BARR;

  RD_B(lds + B0OFF, 1);
  if constexpr (!LAST) stage_half<6>(Ab, kc, 0, lds + A0OFF, t);
  BARR; MM(0, 1); BARR;

  RD_A(lds + A0OFF, 1);
  if constexpr (!LAST) stage_half<5>(Bb, kc, 1, lds + B0OFF, t);
  BARR; MM(1, 1); BARR;

  RD_B(lds + B0OFF, 0);
  if constexpr (!LAST) stage_half<6>(Ab, kc, 1, lds + A0OFF, t);
  BARR; MM(1, 0);
  if constexpr (LAST) asm volatile("s_waitcnt vmcnt(0)" ::: "memory");
  else                asm volatile("s_waitcnt vmcnt(6)" ::: "memory");
  BARR;

  RD_A(lds + A1OFF, 0); RD_B(lds + B1OFF, 0);
  if constexpr (!LAST) stage_half<5>(Bb, kc, 0, lds + B0OFF, t);
  BARR; MM(0, 0); BARR;

  RD_B(lds + B1OFF, 1);
  if constexpr (!LAST) stage_half<6>(Ab, kd, 0, lds + A1OFF, t);
  BARR; MM(0, 1); BARR;

  RD_A(lds + A1OFF, 1);
  if constexpr (!LAST) stage_half<5>(Bb, kd, 1, lds + B1OFF, t);
  BARR; MM(1, 1); BARR;

  RD_B(lds + B1OFF, 0);
  if constexpr (!LAST) stage_half<6>(Ab, kd, 1, lds + A1OFF, t);
  BARR; MM(1, 0);
  if constexpr (!LAST) asm volatile("s_waitcnt vmcnt(6)" ::: "memory");
  BARR;
}

__device__ __forceinline__ void gemm256(const ushort_t* __restrict__ Ab,
                                        const ushort_t* __restrict__ Bb,
                                        ushort_t* lds, f32x4 (&acc)[8][4])
{
  const int t    = threadIdx.x;
  const int lane = t & 63;
  const int wave = t >> 6;
  const int wr   = wave >> 2;
  const int wc   = wave & 3;
  const int arow0 = wr * 128 + (lane & 15);
  const int brow0 = wc * 64  + (lane & 15);
  const int ck0 = (((lane >> 4)    ) ^ (lane & 7)) * 8;
  const int ck1 = ((4 + (lane >> 4)) ^ (lane & 7)) * 8;

  stage_half<6>(Ab,  0, 0, lds + A0OFF, t);
  stage_half<5>(Bb,  0, 1, lds + B0OFF, t);
  stage_half<6>(Ab,  0, 1, lds + A0OFF, t);
  stage_half<5>(Bb,  0, 0, lds + B0OFF, t);
  stage_half<6>(Ab, 64, 0, lds + A1OFF, t);
  stage_half<5>(Bb, 64, 1, lds + B1OFF, t);
  stage_half<6>(Ab, 64, 1, lds + A1OFF, t);
  asm volatile("s_waitcnt vmcnt(6)" ::: "memory");
  BARR;

#pragma unroll 1
  for (int it = 0; it < 7; ++it)
    iter256<false>(Ab, Bb, lds, acc, it * 128, t, arow0, brow0, ck0, ck1);
  iter256<true>(Ab, Bb, lds, acc, 896, t, arow0, brow0, ck0, ck1);
}

// ===========================================================================
// RA-128 core (256Mx128N read-ahead, R11/R12-proven). LDS 96 KB.
// 8 waves as 4M x 2N; wave tile 64x64; acc[4][4].
// ===========================================================================
#define NA0 0
#define NB0 16384
#define NA1 24576
#define NB1 40960

__device__ __forceinline__ void stage_h256(const ushort_t* __restrict__ gb, long ldk,
                                           int k0, int q, ushort_t* lt, int t)
{
#pragma unroll
  for (int j = 0; j < 2; ++j) {
    const int i   = j * 64 + (t >> 3);
    const int row = ((i >> 5) << 6) | (q << 5) | (i & 31);
    const int ch  = (t & 7) ^ (row & 7);
    async_load16(gb + (long)row * ldk + k0 + ch * 8, lt + row * 64 + (t & 7) * 8);
  }
}

__device__ __forceinline__ void stage_h128(const ushort_t* __restrict__ gb, long ldk,
                                           int k0, int q, ushort_t* lt, int t)
{
  const int i   = t >> 3;
  const int row = ((i >> 5) << 6) | (q << 5) | (i & 31);
  const int ch  = (t & 7) ^ (row & 7);
  async_load16(gb + (long)row * ldk + k0 + ch * 8, lt + row * 64 + (t & 7) * 8);
}

#define RD_A4(SET, BASE, QM)                                                  \
  do { _Pragma("unroll") for (int m_ = 0; m_ < 2; ++m_) {                     \
    SET[m_][0] = *(const f16x8*)&lds[(BASE) + (arow_l + (QM)*32 + m_*16) * 64 + ck0]; \
    SET[m_][1] = *(const f16x8*)&lds[(BASE) + (arow_l + (QM)*32 + m_*16) * 64 + ck1]; \
  } } while (0)

#define RD_B4(SET, BASE)                                                      \
  do { _Pragma("unroll") for (int q_ = 0; q_ < 2; ++q_)                       \
    _Pragma("unroll") for (int n_ = 0; n_ < 2; ++n_) {                        \
      SET[q_][n_][0] = *(const f16x8*)&lds[(BASE) + (brow_l + q_*32 + n_*16) * 64 + ck0]; \
      SET[q_][n_][1] = *(const f16x8*)&lds[(BASE) + (brow_l + q_*32 + n_*16) * 64 + ck1]; \
    } } while (0)

#define MM16(AS, BS, QM)                                                      \
  do { __builtin_amdgcn_s_setprio(1);                                         \
  _Pragma("unroll") for (int kh_ = 0; kh_ < 2; ++kh_)                         \
    _Pragma("unroll") for (int m_ = 0; m_ < 2; ++m_)                          \
      _Pragma("unroll") for (int n_ = 0; n_ < 2; ++n_) {                      \
        acc[(QM)*2+m_][n_]   = __builtin_amdgcn_mfma_f32_16x16x32_f16(        \
            AS[m_][kh_], BS[0][n_][kh_], acc[(QM)*2+m_][n_], 0, 0, 0);        \
        acc[(QM)*2+m_][2+n_] = __builtin_amdgcn_mfma_f32_16x16x32_f16(        \
            AS[m_][kh_], BS[1][n_][kh_], acc[(QM)*2+m_][2+n_], 0, 0, 0);      \
      }                                                                       \
  __builtin_amdgcn_s_setprio(0); } while (0)

#define MM16S(AS, BS, QM, SC)                                                 \
  do { __builtin_amdgcn_s_setprio(1);                                         \
  _Pragma("unroll") for (int m_ = 0; m_ < 2; ++m_)                            \
    _Pragma("unroll") for (int kh_ = 0; kh_ < 2; ++kh_) {                     \
      const f16x8 as_ = AS[m_][kh_] * (_Float16)(SC)[(QM)*2+m_];              \
      _Pragma("unroll") for (int n_ = 0; n_ < 2; ++n_) {                      \
        acc[(QM)*2+m_][n_]   = __builtin_amdgcn_mfma_f32_16x16x32_f16(        \
            as_, BS[0][n_][kh_], acc[(QM)*2+m_][n_], 0, 0, 0);                \
        acc[(QM)*2+m_][2+n_] = __builtin_amdgcn_mfma_f32_16x16x32_f16(        \
            as_, BS[1][n_][kh_], acc[(QM)*2+m_][2+n_], 0, 0, 0);              \
      } }                                                                     \
  __builtin_amdgcn_s_setprio(0); } while (0)

template<bool LAST>
__device__ __forceinline__ void iterRA(const ushort_t* __restrict__ Ab,
                                       const ushort_t* __restrict__ Bb,
                                       long lda, long ldb,
                                       ushort_t* lds, f32x4 (&acc)[4][4],
                                       int ka, int t, int arow_l, int brow_l,
                                       int ck0, int ck1,
                                       f16x8 (&aF)[2][2], f16x8 (&aG)[2][2],
                                       f16x8 (&bF)[2][2][2], f16x8 (&bG)[2][2][2])
{
  const int kc = ka + 128, kd = ka + 192;

  RD_A4(aG, NA0, 1);
  if constexpr (!LAST) { stage_h256(Ab, lda, kc, 0, lds + NA0, t);
                         stage_h128(Bb, ldb, kc, 0, lds + NB0, t); }
  BARR;
  MM16(aF, bF, 0);
  if constexpr (LAST) asm volatile("s_waitcnt vmcnt(0)" ::: "memory");
  else                asm volatile("s_waitcnt vmcnt(3)" ::: "memory");
  BARR;

  RD_A4(aF, NA1, 0);
  RD_B4(bG, NB1);
  if constexpr (!LAST) { stage_h256(Ab, lda, kc, 1, lds + NA0, t);
                         stage_h128(Bb, ldb, kc, 1, lds + NB0, t); }
  BARR;
  MM16(aG, bF, 1);
  BARR;

  RD_A4(aG, NA1, 1);
  if constexpr (!LAST) { stage_h256(Ab, lda, kd, 0, lds + NA1, t);
                         stage_h128(Bb, ldb, kd, 0, lds + NB1, t); }
  BARR;
  MM16(aF, bG, 0);
  if constexpr (!LAST) asm volatile("s_waitcnt vmcnt(3)" ::: "memory");
  BARR;

  if constexpr (!LAST) {
    RD_A4(aF, NA0, 0);
    RD_B4(bF, NB0);
    stage_h256(Ab, lda, kd, 1, lds + NA1, t);
    stage_h128(Bb, ldb, kd, 1, lds + NB1, t);
  }
  BARR;
  MM16(aG, bG, 1);
  BARR;
}

template<bool LAST>
__device__ __forceinline__ void pv_iterRA(const ushort_t* __restrict__ Ab,
                                          const ushort_t* __restrict__ Bb,
                                          ushort_t* lds, const float (*ScL)[256],
                                          f32x4 (&acc)[4][4],
                                          int ka, int t, int arow_l, int brow_l,
                                          int ck0, int ck1,
                                          f16x8 (&aF)[2][2], f16x8 (&aG)[2][2],
                                          f16x8 (&bF)[2][2][2], f16x8 (&bG)[2][2][2])
{
  const int kc = ka + 128, kd = ka + 192;
  const int cba = ka >> 6;
  float sa4[4], sb4[4];
#pragma unroll
  for (int s = 0; s < 4; ++s) {
    sa4[s] = ScL[cba][arow_l + s * 16];
    sb4[s] = ScL[cba + 1][arow_l + s * 16];
  }

  RD_A4(aG, NA0, 1);
  if constexpr (!LAST) { stage_h256(Ab, 2048, kc, 0, lds + NA0, t);
                         stage_h128(Bb, 2048, kc, 0, lds + NB0, t); }
  BARR;
  MM16S(aF, bF, 0, sa4);
  if constexpr (LAST) asm volatile("s_waitcnt vmcnt(0)" ::: "memory");
  else                asm volatile("s_waitcnt vmcnt(3)" ::: "memory");
  BARR;

  RD_A4(aF, NA1, 0);
  RD_B4(bG, NB1);
  if constexpr (!LAST) { stage_h256(Ab, 2048, kc, 1, lds + NA0, t);
                         stage_h128(Bb, 2048, kc, 1, lds + NB0, t); }
  BARR;
  MM16S(aG, bF, 1, sa4);
  BARR;

  RD_A4(aG, NA1, 1);
  if constexpr (!LAST) { stage_h256(Ab, 2048, kd, 0, lds + NA1, t);
                         stage_h128(Bb, 2048, kd, 0, lds + NB1, t); }
  BARR;
  MM16S(aF, bG, 0, sb4);
  if constexpr (!LAST) asm volatile("s_waitcnt vmcnt(3)" ::: "memory");
  BARR;

  if constexpr (!LAST) {
    RD_A4(aF, NA0, 0);
    RD_B4(bF, NB0);
    stage_h256(Ab, 2048, kd, 1, lds + NA1, t);
    stage_h128(Bb, 2048, kd, 1, lds + NB1, t);
  }
  BARR;
  MM16S(aG, bG, 1, sb4);
  BARR;
}

#define PROLOGUE_RA(LDA, LDB)                               \
  do {                                                      \
    stage_h256(Ab, (LDA),  0, 0, lds + NA0, t);             \
    stage_h128(Bb, (LDB),  0, 0, lds + NB0, t);             \
    stage_h256(Ab, (LDA),  0, 1, lds + NA0, t);             \
    stage_h128(Bb, (LDB),  0, 1, lds + NB0, t);             \
    asm volatile("s_waitcnt vmcnt(0)" ::: "memory");        \
    BARR;                                                   \
    RD_A4(aF, NA0, 0);                                      \
    RD_B4(bF, NB0);                                         \
    stage_h256(Ab, (LDA), 64, 0, lds + NA1, t);             \
    stage_h128(Bb, (LDB), 64, 0, lds + NB1, t);             \
    stage_h256(Ab, (LDA), 64, 1, lds + NA1, t);             \
    stage_h128(Bb, (LDB), 64, 1, lds + NB1, t);             \
    BARR;                                                   \
  } while (0)

// ---------------------------------------------------------------------------
// QK-projection on the 256x256 core. A = Xh [8192][1024], BT = Wt rows
// 0..2047 (Wq^T|Wk^T). grid (8, M/256) = 256 blocks = 1 round.
// ---------------------------------------------------------------------------
__global__ __launch_bounds__(512, 2)
void qkproj_kernel(const ushort_t* __restrict__ A, const ushort_t* __restrict__ BT,
                   const float* __restrict__ bq, const float* __restrict__ bk,
                   __half* __restrict__ Qh, __half* __restrict__ Kh)
{
  __shared__ __align__(16) ushort_t lds[65536];   // 128 KB

  const int nb = gridDim.x * gridDim.y;           // 256, %8==0
  int id = blockIdx.y * gridDim.x + blockIdx.x;
  id = (id & 7) * (nb >> 3) + (id >> 3);          // bijective XCD swizzle
  const int bx = id % gridDim.x;                  // 0..7 (N-tile of 256 over Q|K)
  const int by = id / gridDim.x;                  // M-tile of 256

  const ushort_t* Ab = A  + (long)by * 256 * 1024;
  const ushort_t* Bb = BT + (long)bx * 256 * 1024;

  f32x4 acc[8][4];
  const f32x4 zero = {0.0f, 0.0f, 0.0f, 0.0f};
#pragma unroll
  for (int i = 0; i < 8; ++i)
#pragma unroll
    for (int j = 0; j < 4; ++j) acc[i][j] = zero;

  gemm256(Ab, Bb, lds, acc);

  const int t = threadIdx.x, lane = t & 63, wave = t >> 6;
  const int wr = wave >> 2, wc = wave & 3;
  const int er = (lane >> 4) * 4, ec = lane & 15;
  const int tgt = bx >> 2;                        // 0:Q 1:K (uniform)
  const float* bias = (tgt == 0) ? bq : bk;
  __half* o = (tgt == 0) ? Qh : Kh;

#pragma unroll
  for (int ni = 0; ni < 4; ++ni) {
    const int col = (bx & 3) * 256 + wc * 64 + ni * 16 + ec;   // 0..1023
    const float bval = bias[col];
#pragma unroll
    for (int mi = 0; mi < 8; ++mi) {
      const long grow0 = (long)by * 256 + wr * 128 + mi * 16 + er;
#pragma unroll
      for (int r = 0; r < 4; ++r)
        o[(grow0 + r) * 1024 + col] = __float2half(acc[mi][ni][r] + bval);
    }
  }
}

// ---------------------------------------------------------------------------
// V-projection on the RA-128 core. BT rows 2048+bx*128. grid (8, M/256).
// ---------------------------------------------------------------------------
__global__ __launch_bounds__(512, 2)
void vproj_kernel(const ushort_t* __restrict__ A, const ushort_t* __restrict__ BT,
                  const float* __restrict__ bvp, ushort_t* __restrict__ Vt)
{
  __shared__ __align__(16) ushort_t lds[49152];   // 96 KB

  const int nb = gridDim.x * gridDim.y;           // 256, %8==0
  int id = blockIdx.y * gridDim.x + blockIdx.x;
  id = (id & 7) * (nb >> 3) + (id >> 3);
  const int bx = id % gridDim.x;                  // 0..7 (V N-tile of 128)
  const int by = id / gridDim.x;                  // M-tile of 256

  const ushort_t* Ab = A  + (long)by * 256 * 1024;
  const ushort_t* Bb = BT + (long)(16 + bx) * 128 * 1024;

  const int t    = threadIdx.x;
  const int lane = t & 63;
  const int wave = t >> 6;
  const int wr   = wave >> 1;                     // 0..3
  const int wc   = wave & 1;                      // 0..1
  const int arow_l = wr * 64 + (lane & 15);
  const int brow_l = wc * 64 + (lane & 15);
  const int ck0 = (((lane >> 4)    ) ^ (lane & 7)) * 8;
  const int ck1 = ((4 + (lane >> 4)) ^ (lane & 7)) * 8;

  f32x4 acc[4][4];
  const f32x4 zero = {0.0f, 0.0f, 0.0f, 0.0f};
#pragma unroll
  for (int i = 0; i < 4; ++i)
#pragma unroll
    for (int j = 0; j < 4; ++j) acc[i][j] = zero;

  f16x8 aF[2][2], aG[2][2], bF[2][2][2], bG[2][2][2];

  PROLOGUE_RA(1024, 1024);
#pragma unroll 1
  for (int it = 0; it < 7; ++it)
    iterRA<false>(Ab, Bb, 1024, 1024, lds, acc, it * 128, t, arow_l, brow_l,
                  ck0, ck1, aF, aG, bF, bG);
  iterRA<true>(Ab, Bb, 1024, 1024, lds, acc, 896, t, arow_l, brow_l,
               ck0, ck1, aF, aG, bF, bG);

  const int er = (lane >> 4) * 4, ec = lane & 15;
#pragma unroll
  for (int ni = 0; ni < 4; ++ni) {
    const int col = bx * 128 + wc * 64 + ni * 16 + ec;   // 0..1023
    const float bval = bvp[col];
#pragma unroll
    for (int mi = 0; mi < 4; ++mi) {
      const long grow0 = (long)by * 256 + wr * 64 + mi * 16 + er;
      const long b  = grow0 >> 11;                // batch
      const long ml = grow0 & 2047;               // aligned to 4
      f16x4 v4;
#pragma unroll
      for (int r = 0; r < 4; ++r) v4[r] = (_Float16)(acc[mi][ni][r] + bval);
      *(f16x4*)&Vt[b * 2097152 + (long)col * 2048 + ml] = v4;
    }
  }
}

// ---------------------------------------------------------------------------
// QK^T on the 256x256 core with fused partial softmax, 64-col chunks.
// Wave (wr,wc) owns 128 rows x 64 cols; chunk cc = bx*4+wc (0..31).
// grid (8, 8, 4) = 256 blocks = 1 round.
// ---------------------------------------------------------------------------
__global__ __launch_bounds__(512, 2)
void qkattn_kernel(const ushort_t* __restrict__ Q, const ushort_t* __restrict__ Kh,
                   __half* __restrict__ S, float* __restrict__ PM, float* __restrict__ PS)
{
  __shared__ __align__(16) ushort_t lds[65536];

  const int nb = gridDim.x * gridDim.y;           // 64, %8==0
  int id = blockIdx.y * gridDim.x + blockIdx.x;
  id = (id & 7) * (nb >> 3) + (id >> 3);
  const int bx = id % gridDim.x;                  // 0..7 (K-tile of 256)
  const int by = id / gridDim.x;                  // 0..7 (Q-tile of 256)
  const long z = blockIdx.z;

  const ushort_t* Ab = Q  + z * 2048 * 1024 + (long)by * 256 * 1024;
  const ushort_t* Bb = Kh + z * 2048 * 1024 + (long)bx * 256 * 1024;
  __half* Sb = S + z * 2048 * 2048;

  f32x4 acc[8][4];
  const f32x4 zero = {0.0f, 0.0f, 0.0f, 0.0f};
#pragma unroll
  for (int i = 0; i < 8; ++i)
#pragma unroll
    for (int j = 0; j < 4; ++j) acc[i][j] = zero;

  gemm256(Ab, Bb, lds, acc);

  const int t = threadIdx.x, lane = t & 63, wave = t >> 6;
  const int wr = wave >> 2, wc = wave & 3;
  const int er = (lane >> 4) * 4, ec = lane & 15;
  const int cc = bx * 4 + wc;                     // 0..31
  float* PMb = PM + z * 32 * 2048 + (long)cc * 2048;
  float* PSb = PS + z * 32 * 2048 + (long)cc * 2048;

#pragma unroll
  for (int m8 = 0; m8 < 8; ++m8)
#pragma unroll
    for (int r = 0; r < 4; ++r) {
      float m = fmaxf(fmaxf(acc[m8][0][r], acc[m8][1][r]),
                      fmaxf(acc[m8][2][r], acc[m8][3][r]));
      m = fmaxf(m, __shfl_xor(m, 1));   // reduce over the 16 ec lanes
      m = fmaxf(m, __shfl_xor(m, 2));
      m = fmaxf(m, __shfl_xor(m, 4));
      m = fmaxf(m, __shfl_xor(m, 8));
      float s = 0.0f;
#pragma unroll
      for (int n4 = 0; n4 < 4; ++n4) {
        const float e = __expf(acc[m8][n4][r] - m);
        acc[m8][n4][r] = e;
        s += e;
      }
      s += __shfl_xor(s, 1);
      s += __shfl_xor(s, 2);
      s += __shfl_xor(s, 4);
      s += __shfl_xor(s, 8);
      if (ec == 0) {
        const long row = (long)by * 256 + wr * 128 + m8 * 16 + er + r;
        PMb[row] = m;
        PSb[row] = s;
      }
    }

  // store p_unnorm = exp(s - m_chunk) fp16
#pragma unroll
  for (int n4 = 0; n4 < 4; ++n4) {
    const long col = (long)bx * 256 + wc * 64 + n4 * 16 + ec;
#pragma unroll
    for (int m8 = 0; m8 < 8; ++m8)
#pragma unroll
      for (int r = 0; r < 4; ++r) {
        const long grow = (long)by * 256 + wr * 128 + m8 * 16 + er + r;
        Sb[grow * 2048 + col] = __float2half(acc[m8][n4][r]);
      }
  }
}

// ---------------------------------------------------------------------------
// PV on the RA-128 core, softmax-reduce fused into the prologue.
// grid (8, 8, 4) = 256 blocks. K = 2048.
// ---------------------------------------------------------------------------
__global__ __launch_bounds__(512, 2)
void pv_ra_kernel(const ushort_t* __restrict__ S, const ushort_t* __restrict__ Vt,
                  const float* __restrict__ PM, const float* __restrict__ PS,
                  float* __restrict__ Out)
{
  __shared__ __align__(16) ushort_t lds[49152];   // 96 KB
  __shared__ float ScL[32][256];                  // +32 KB = 128 KB

  const int nb = gridDim.x * gridDim.y;           // 64, %8==0
  int id = blockIdx.y * gridDim.x + blockIdx.x;
  id = (id & 7) * (nb >> 3) + (id >> 3);
  const int bx = id % gridDim.x;                  // N-tile (Out cols / Vt rows)
  const int by = id / gridDim.x;                  // M-tile (S rows)
  const long z = blockIdx.z;

  const ushort_t* Ab = S  + z * 4194304 + (long)by * 256 * 2048;
  const ushort_t* Bb = Vt + z * 2097152 + (long)bx * 128 * 2048;
  float* Cb = Out + z * 2048 * 1024;

  const int t = threadIdx.x;

  // ---- fused softmax reduce for this block's 256 rows ----
  if (t < 256) {
    const long row = (long)by * 256 + t;
    const float* PMb = PM + z * 32 * 2048;
    const float* PSb = PS + z * 32 * 2048;
    float pm[32];
    float m = -3.4e38f;
#pragma unroll
    for (int cb = 0; cb < 32; ++cb) {
      pm[cb] = PMb[(long)cb * 2048 + row];
      m = fmaxf(m, pm[cb]);
    }
    float l = 0.0f;
#pragma unroll
    for (int cb = 0; cb < 32; ++cb)
      l += PSb[(long)cb * 2048 + row] * __expf(pm[cb] - m);
    const float inv = 1.0f / l;
#pragma unroll
    for (int cb = 0; cb < 32; ++cb)
      ScL[cb][t] = __expf(pm[cb] - m) * inv;
  }
  __syncthreads();   // full drain; ScL visible; vmcnt clean before staging

  const int lane = t & 63;
  const int wave = t >> 6;
  const int wr   = wave >> 1;
  const int wc   = wave & 1;
  const int arow_l = wr * 64 + (lane & 15);
  const int brow_l = wc * 64 + (lane & 15);
  const int ck0 = (((lane >> 4)    ) ^ (lane & 7)) * 8;
  const int ck1 = ((4 + (lane >> 4)) ^ (lane & 7)) * 8;

  f32x4 acc[4][4];
  const f32x4 zero = {0.0f, 0.0f, 0.0f, 0.0f};
#pragma unroll
  for (int i = 0; i < 4; ++i)
#pragma unroll
    for (int j = 0; j < 4; ++j) acc[i][j] = zero;

  f16x8 aF[2][2], aG[2][2], bF[2][2][2], bG[2][2][2];

  PROLOGUE_RA(2048, 2048);
#pragma unroll 1
  for (int it = 0; it < 15; ++it)
    pv_iterRA<false>(Ab, Bb, lds, ScL, acc, it * 128, t, arow_l, brow_l,
                     ck0, ck1, aF, aG, bF, bG);
  pv_iterRA<true>(Ab, Bb, lds, ScL, acc, 1920, t, arow_l, brow_l,
                  ck0, ck1, aF, aG, bF, bG);

  const int er = (lane >> 4) * 4, ec = lane & 15;
#pragma unroll
  for (int ni = 0; ni < 4; ++ni) {
    const int gcol = bx * 128 + wc * 64 + ni * 16 + ec;
#pragma unroll
    for (int mi = 0; mi < 4; ++mi) {
#pragma unroll
      for (int r = 0; r < 4; ++r) {
        const long grow = (long)by * 256 + wr * 64 + mi * 16 + er + r;
        Cb[grow * 1024 + gcol] = acc[mi][ni][r];
      }
    }
  }
}

// ---------------------------------------------------------------------------
// Fused prep: z<3 -> weight transpose+cvt; z>=3 -> X fp32->fp16 slice.
// grid (32, 32, 7), 256 thr.
// ---------------------------------------------------------------------------
__global__ __launch_bounds__(256)
void prep_kernel(const float* __restrict__ W0, const float* __restrict__ W1,
                 const float* __restrict__ W2, __half* __restrict__ dstW,
                 const float* __restrict__ X, __half* __restrict__ Xh)
{
  __shared__ float tile[32][33];
  const int z = blockIdx.z;
  if (z < 3) {
    const float* src = (z == 0) ? W0 : (z == 1) ? W1 : W2;
    __half* d = dstW + (long)z * 1024 * 1024;
    const int c0 = blockIdx.x * 32;
    const int r0 = blockIdx.y * 32;
    const int tx = threadIdx.x & 31;
    const int ty = threadIdx.x >> 5;
#pragma unroll
    for (int i = 0; i < 32; i += 8)
      tile[ty + i][tx] = src[(long)(r0 + ty + i) * 1024 + (c0 + tx)];
    __syncthreads();
#pragma unroll
    for (int i = 0; i < 32; i += 8)
      d[(long)(c0 + ty + i) * 1024 + (r0 + tx)] = __float2half(tile[tx][ty + i]);
  } else {
    const int bid = blockIdx.y * gridDim.x + blockIdx.x;        // 0..1023
    const long i = (((long)(z - 3) * 1024 + bid) * 256 + threadIdx.x) * 8;
    const float4 a = *(const float4*)(X + i);
    const float4 b = *(const float4*)(X + i + 4);
    f16x8 h;
    h[0] = (_Float16)a.x; h[1] = (_Float16)a.y; h[2] = (_Float16)a.z; h[3] = (_Float16)a.w;
    h[4] = (_Float16)b.x; h[5] = (_Float16)b.y; h[6] = (_Float16)b.z; h[7] = (_Float16)b.w;
    *(f16x8*)((ushort_t*)Xh + i) = h;
  }
}

// ---------------------------------------------------------------------------
extern "C" void kernel_launch(void* const* d_in, const int* in_sizes, int n_in,
                              void* d_out, int out_size, void* d_ws, size_t ws_size,
                              hipStream_t stream)
{
  const int  Bb = 4, Nn = 2048, Dd = 1024;
  const long BN = (long)Bb * Nn;  // 8192

  const float* X  = (const float*)d_in[0];
  const float* Wq = (const float*)d_in[1];
  const float* bq = (const float*)d_in[2];
  const float* Wk = (const float*)d_in[3];
  const float* bk = (const float*)d_in[4];
  const float* Wv = (const float*)d_in[5];
  const float* bv = (const float*)d_in[6];
  float* Out      = (float*)d_out;

  uint8_t* w = (uint8_t*)d_ws;
  ushort_t* Wt = (ushort_t*)w;  w += (size_t)3 * Dd * Dd * 2;  // Wq^T|Wk^T|Wv^T fp16

  const size_t statsBytes = (size_t)Bb * 32 * Nn * 4;   // 1 MB each
  const size_t fullNeed = (size_t)3 * Dd * Dd * 2       // Wt
                        + 4 * ((size_t)BN * Dd * 2)     // Xh, Q, K, Vt fp16
                        + (size_t)Bb * Nn * Nn * 2      // S fp16
                        + 2 * statsBytes;               // PM, PS

  if (ws_size >= fullNeed) {
    ushort_t* Xh = (ushort_t*)w;  w += (size_t)BN * Dd * 2;
    ushort_t* Q  = (ushort_t*)w;  w += (size_t)BN * Dd * 2;
    ushort_t* Kb = (ushort_t*)w;  w += (size_t)BN * Dd * 2;
    ushort_t* Vt = (ushort_t*)w;  w += (size_t)BN * Dd * 2;  // [B][Dd][Nn]
    ushort_t* S  = (ushort_t*)w;  w += (size_t)Bb * Nn * Nn * 2;
    float*    PM = (float*)w;     w += statsBytes;
    float*    PS = (float*)w;

    prep_kernel<<<dim3(32, 32, 7), 256, 0, stream>>>(Wq, Wk, Wv, (__half*)Wt, X, (__half*)Xh);

    qkproj_kernel<<<dim3(8, BN / 256, 1), 512, 0, stream>>>(
        Xh, Wt, bq, bk, (__half*)Q, (__half*)Kb);

    vproj_kernel<<<dim3(8, BN / 256, 1), 512, 0, stream>>>(Xh, Wt, bv, Vt);

    qkattn_kernel<<<dim3(Nn / 256, Nn / 256, Bb), 512, 0, stream>>>(
        Q, Kb, (__half*)S, PM, PS);

    pv_ra_kernel<<<dim3(Dd / 128, Nn / 256, Bb), 512, 0, stream>>>(
        S, Vt, PM, PS, Out);
  } else {
    // Per-batch fallback (~32 MB ws): same cores, z-extent 1
    ushort_t* Xh = (ushort_t*)w;  w += (size_t)Nn * Dd * 2;
    ushort_t* Q  = (ushort_t*)w;  w += (size_t)Nn * Dd * 2;
    ushort_t* Kb = (ushort_t*)w;  w += (size_t)Nn * Dd * 2;
    ushort_t* Vt = (ushort_t*)w;  w += (size_t)Nn * Dd * 2;
    ushort_t* S  = (ushort_t*)w;  w += (size_t)Nn * Nn * 2;
    float*    PM = (float*)w;     w += (size_t)32 * Nn * 4;
    float*    PS = (float*)w;

    for (int b = 0; b < Bb; ++b) {
      const float* Xb = X + (long)b * Nn * Dd;
      prep_kernel<<<dim3(32, 32, b == 0 ? 4 : 1), 256, 0, stream>>>(
          Wq, Wk, Wv, (__half*)Wt, Xb, (__half*)Xh);  // z=3 slice converts Xb
      qkproj_kernel<<<dim3(8, Nn / 256, 1), 512, 0, stream>>>(
          Xh, Wt, bq, bk, (__half*)Q, (__half*)Kb);
      vproj_kernel<<<dim3(8, Nn / 256, 1), 512, 0, stream>>>(Xh, Wt, bv, Vt);
      qkattn_kernel<<<dim3(Nn / 256, Nn / 256, 1), 512, 0, stream>>>(
          Q, Kb, (__half*)S, PM, PS);
      pv_ra_kernel<<<dim3(Dd / 128, Nn / 256, 1), 512, 0, stream>>>(
          S, Vt, PM, PS, Out + (long)b * Nn * Dd);
    }
  }
}

// Round 8
// 246.045 us; speedup vs baseline: 1.5615x; 1.0516x over previous
//
#include <hip/hip_runtime.h>
#include <hip/hip_bf16.h>
#include <hip/hip_fp16.h>
#include <stdint.h>
#include <math.h>

// ---------------------------------------------------------------------------
// AttentionLayer: Q=XWq+bq, K=XWk+bk, V=XWv+bv; O = softmax(QK^T) V
// B=4, N=2048, D=1024. fp32 I/O; internals fp16, accumulation fp32.
// R14: epilogue fixes (cores byte-frozen from R13):
//  - qkattn softmax -> breadth-first shuffle reduction (32 independent
//    chains per step instead of 32 serial 8-deep chains; same math order)
//  - qkattn/qkproj stores via per-wave LDS slice (64x72-pad halves) ->
//    f16x8 coalesced global stores (kills 2.5x HBM write amplification)
//  - vproj Vt store via transposed [col][ml] LDS slice (kills 8x write amp)
//  - launch order prep -> vproj -> qkproj -> qkattn -> pv (Q/K hot in L2)
// ---------------------------------------------------------------------------

typedef unsigned short ushort_t;
typedef __attribute__((ext_vector_type(8))) _Float16  f16x8;
typedef __attribute__((ext_vector_type(4))) _Float16  f16x4;
typedef __attribute__((ext_vector_type(4))) float     f32x4;

__device__ __forceinline__ void async_load16(const void* g, void* l) {
  __builtin_amdgcn_global_load_lds(
      (const __attribute__((address_space(1))) void*)g,
      (__attribute__((address_space(3))) void*)l, 16, 0, 0);
}

#define BARR do { __builtin_amdgcn_sched_barrier(0); \
                  __builtin_amdgcn_s_barrier();      \
                  __builtin_amdgcn_sched_barrier(0); } while (0)

#define LGKM0 do { asm volatile("s_waitcnt lgkmcnt(0)" ::: "memory"); \
                   __builtin_amdgcn_sched_barrier(0); } while (0)

// ===========================================================================
// 256x256 8-phase core (R8-proven, same-phase reads). LDS 128 KB.
// 8 waves as 2M x 4N; wave tile 128x64; acc[8][4].
// ===========================================================================
#define A0OFF 0
#define B0OFF 16384
#define A1OFF 32768
#define B1OFF 49152

template<int SHIFT>
__device__ __forceinline__ void stage_half(const ushort_t* __restrict__ gb,
                                           int k0, int q, ushort_t* lt, int t)
{
#pragma unroll
  for (int j = 0; j < 2; ++j) {
    const int i   = j * 64 + (t >> 3);
    const int row = ((i >> SHIFT) << (SHIFT + 1)) | (q << SHIFT) | (i & ((1 << SHIFT) - 1));
    const int ch  = (t & 7) ^ (row & 7);
    async_load16(gb + (long)row * 1024 + k0 + ch * 8, lt + row * 64 + (t & 7) * 8);
  }
}

#define RD_A(TP, QM)                                                          \
  do { _Pragma("unroll") for (int m_ = 0; m_ < 4; ++m_) {                     \
    af[m_][0] = *(const f16x8*)&(TP)[(arow0 + (QM)*64 + m_*16) * 64 + ck0];   \
    af[m_][1] = *(const f16x8*)&(TP)[(arow0 + (QM)*64 + m_*16) * 64 + ck1];   \
  } } while (0)

#define RD_B(TP, QN)                                                          \
  do { _Pragma("unroll") for (int n_ = 0; n_ < 2; ++n_) {                     \
    bf[n_][0] = *(const f16x8*)&(TP)[(brow0 + (QN)*32 + n_*16) * 64 + ck0];   \
    bf[n_][1] = *(const f16x8*)&(TP)[(brow0 + (QN)*32 + n_*16) * 64 + ck1];   \
  } } while (0)

#define MM(QM, QN)                                                            \
  do { __builtin_amdgcn_s_setprio(1);                                         \
  _Pragma("unroll") for (int kh_ = 0; kh_ < 2; ++kh_)                         \
    _Pragma("unroll") for (int m_ = 0; m_ < 4; ++m_)                          \
      _Pragma("unroll") for (int n_ = 0; n_ < 2; ++n_)                        \
        acc[(QM)*4+m_][(QN)*2+n_] = __builtin_amdgcn_mfma_f32_16x16x32_f16(   \
            af[m_][kh_], bf[n_][kh_], acc[(QM)*4+m_][(QN)*2+n_], 0, 0, 0);    \
  __builtin_amdgcn_s_setprio(0); } while (0)

template<bool LAST>
__device__ __forceinline__ void iter256(const ushort_t* __restrict__ Ab,
                                        const ushort_t* __restrict__ Bb,
                                        ushort_t* lds, f32x4 (&acc)[8][4],
                                        int ka, int t, int arow0, int brow0,
                                        int ck0, int ck1)
{
  const int kb = ka + 64, kc = ka + 128, kd = ka + 192;
  f16x8 af[4][2], bf[2][2];

  RD_A(lds + A0OFF, 0); RD_B(lds + B0OFF, 0);
  stage_half<5>(Bb, kb, 0, lds + B1OFF, t);
  BARR; MM(0, 0); BARR;

  RD_B(lds + B0OFF, 1);
  if constexpr (!LAST) stage_half<6>(Ab, kc, 0, lds + A0OFF, t);
  BARR; MM(0, 1); BARR;

  RD_A(lds + A0OFF, 1);
  if constexpr (!LAST) stage_half<5>(Bb, kc, 1, lds + B0OFF, t);
  BARR; MM(1, 1); BARR;

  RD_B(lds + B0OFF, 0);
  if constexpr (!LAST) stage_half<6>(Ab, kc, 1, lds + A0OFF, t);
  BARR; MM(1, 0);
  if constexpr (LAST) asm volatile("s_waitcnt vmcnt(0)" ::: "memory");
  else                asm volatile("s_waitcnt vmcnt(6)" ::: "memory");
  BARR;

  RD_A(lds + A1OFF, 0); RD_B(lds + B1OFF, 0);
  if constexpr (!LAST) stage_half<5>(Bb, kc, 0, lds + B0OFF, t);
  BARR; MM(0, 0); BARR;

  RD_B(lds + B1OFF, 1);
  if constexpr (!LAST) stage_half<6>(Ab, kd, 0, lds + A1OFF, t);
  BARR; MM(0, 1); BARR;

  RD_A(lds + A1OFF, 1);
  if constexpr (!LAST) stage_half<5>(Bb, kd, 1, lds + B1OFF, t);
  BARR; MM(1, 1); BARR;

  RD_B(lds + B1OFF, 0);
  if constexpr (!LAST) stage_half<6>(Ab, kd, 1, lds + A1OFF, t);
  BARR; MM(1, 0);
  if constexpr (!LAST) asm volatile("s_waitcnt vmcnt(6)" ::: "memory");
  BARR;
}

__device__ __forceinline__ void gemm256(const ushort_t* __restrict__ Ab,
                                        const ushort_t* __restrict__ Bb,
                                        ushort_t* lds, f32x4 (&acc)[8][4])
{
  const int t    = threadIdx.x;
  const int lane = t & 63;
  const int wave = t >> 6;
  const int wr   = wave >> 2;
  const int wc   = wave & 3;
  const int arow0 = wr * 128 + (lane & 15);
  const int brow0 = wc * 64  + (lane & 15);
  const int ck0 = (((lane >> 4)    ) ^ (lane & 7)) * 8;
  const int ck1 = ((4 + (lane >> 4)) ^ (lane & 7)) * 8;

  stage_half<6>(Ab,  0, 0, lds + A0OFF, t);
  stage_half<5>(Bb,  0, 1, lds + B0OFF, t);
  stage_half<6>(Ab,  0, 1, lds + A0OFF, t);
  stage_half<5>(Bb,  0, 0, lds + B0OFF, t);
  stage_half<6>(Ab, 64, 0, lds + A1OFF, t);
  stage_half<5>(Bb, 64, 1, lds + B1OFF, t);
  stage_half<6>(Ab, 64, 1, lds + A1OFF, t);
  asm volatile("s_waitcnt vmcnt(6)" ::: "memory");
  BARR;

#pragma unroll 1
  for (int it = 0; it < 7; ++it)
    iter256<false>(Ab, Bb, lds, acc, it * 128, t, arow0, brow0, ck0, ck1);
  iter256<true>(Ab, Bb, lds, acc, 896, t, arow0, brow0, ck0, ck1);
}

// ===========================================================================
// RA-128 core (256Mx128N read-ahead, R11/R12-proven). LDS 96 KB.
// 8 waves as 4M x 2N; wave tile 64x64; acc[4][4].
// ===========================================================================
#define NA0 0
#define NB0 16384
#define NA1 24576
#define NB1 40960

__device__ __forceinline__ void stage_h256(const ushort_t* __restrict__ gb, long ldk,
                                           int k0, int q, ushort_t* lt, int t)
{
#pragma unroll
  for (int j = 0; j < 2; ++j) {
    const int i   = j * 64 + (t >> 3);
    const int row = ((i >> 5) << 6) | (q << 5) | (i & 31);
    const int ch  = (t & 7) ^ (row & 7);
    async_load16(gb + (long)row * ldk + k0 + ch * 8, lt + row * 64 + (t & 7) * 8);
  }
}

__device__ __forceinline__ void stage_h128(const ushort_t* __restrict__ gb, long ldk,
                                           int k0, int q, ushort_t* lt, int t)
{
  const int i   = t >> 3;
  const int row = ((i >> 5) << 6) | (q << 5) | (i & 31);
  const int ch  = (t & 7) ^ (row & 7);
  async_load16(gb + (long)row * ldk + k0 + ch * 8, lt + row * 64 + (t & 7) * 8);
}

#define RD_A4(SET, BASE, QM)                                                  \
  do { _Pragma("unroll") for (int m_ = 0; m_ < 2; ++m_) {                     \
    SET[m_][0] = *(const f16x8*)&lds[(BASE) + (arow_l + (QM)*32 + m_*16) * 64 + ck0]; \
    SET[m_][1] = *(const f16x8*)&lds[(BASE) + (arow_l + (QM)*32 + m_*16) * 64 + ck1]; \
  } } while (0)

#define RD_B4(SET, BASE)                                                      \
  do { _Pragma("unroll") for (int q_ = 0; q_ < 2; ++q_)                       \
    _Pragma("unroll") for (int n_ = 0; n_ < 2; ++n_) {                        \
      SET[q_][n_][0] = *(const f16x8*)&lds[(BASE) + (brow_l + q_*32 + n_*16) * 64 + ck0]; \
      SET[q_][n_][1] = *(const f16x8*)&lds[(BASE) + (brow_l + q_*32 + n_*16) * 64 + ck1]; \
    } } while (0)

#define MM16(AS, BS, QM)                                                      \
  do { __builtin_amdgcn_s_setprio(1);                                         \
  _Pragma("unroll") for (int kh_ = 0; kh_ < 2; ++kh_)                         \
    _Pragma("unroll") for (int m_ = 0; m_ < 2; ++m_)                          \
      _Pragma("unroll") for (int n_ = 0; n_ < 2; ++n_) {                      \
        acc[(QM)*2+m_][n_]   = __builtin_amdgcn_mfma_f32_16x16x32_f16(        \
            AS[m_][kh_], BS[0][n_][kh_], acc[(QM)*2+m_][n_], 0, 0, 0);        \
        acc[(QM)*2+m_][2+n_] = __builtin_amdgcn_mfma_f32_16x16x32_f16(        \
            AS[m_][kh_], BS[1][n_][kh_], acc[(QM)*2+m_][2+n_], 0, 0, 0);      \
      }                                                                       \
  __builtin_amdgcn_s_setprio(0); } while (0)

#define MM16S(AS, BS, QM, SC)                                                 \
  do { __builtin_amdgcn_s_setprio(1);                                         \
  _Pragma("unroll") for (int m_ = 0; m_ < 2; ++m_)                            \
    _Pragma("unroll") for (int kh_ = 0; kh_ < 2; ++kh_) {                     \
      const f16x8 as_ = AS[m_][kh_] * (_Float16)(SC)[(QM)*2+m_];              \
      _Pragma("unroll") for (int n_ = 0; n_ < 2; ++n_) {                      \
        acc[(QM)*2+m_][n_]   = __builtin_amdgcn_mfma_f32_16x16x32_f16(        \
            as_, BS[0][n_][kh_], acc[(QM)*2+m_][n_], 0, 0, 0);                \
        acc[(QM)*2+m_][2+n_] = __builtin_amdgcn_mfma_f32_16x16x32_f16(        \
            as_, BS[1][n_][kh_], acc[(QM)*2+m_][2+n_], 0, 0, 0);              \
      } }                                                                     \
  __builtin_amdgcn_s_setprio(0); } while (0)

template<bool LAST>
__device__ __forceinline__ void iterRA(const ushort_t* __restrict__ Ab,
                                       const ushort_t* __restrict__ Bb,
                                       long lda, long ldb,
                                       ushort_t* lds, f32x4 (&acc)[4][4],
                                       int ka, int t, int arow_l, int brow_l,
                                       int ck0, int ck1,
                                       f16x8 (&aF)[2][2], f16x8 (&aG)[2][2],
                                       f16x8 (&bF)[2][2][2], f16x8 (&bG)[2][2][2])
{
  const int kc = ka + 128, kd = ka + 192;

  RD_A4(aG, NA0, 1);
  if constexpr (!LAST) { stage_h256(Ab, lda, kc, 0, lds + NA0, t);
                         stage_h128(Bb, ldb, kc, 0, lds + NB0, t); }
  BARR;
  MM16(aF, bF, 0);
  if constexpr (LAST) asm volatile("s_waitcnt vmcnt(0)" ::: "memory");
  else                asm volatile("s_waitcnt vmcnt(3)" ::: "memory");
  BARR;

  RD_A4(aF, NA1, 0);
  RD_B4(bG, NB1);
  if constexpr (!LAST) { stage_h256(Ab, lda, kc, 1, lds + NA0, t);
                         stage_h128(Bb, ldb, kc, 1, lds + NB0, t); }
  BARR;
  MM16(aG, bF, 1);
  BARR;

  RD_A4(aG, NA1, 1);
  if constexpr (!LAST) { stage_h256(Ab, lda, kd, 0, lds + NA1, t);
                         stage_h128(Bb, ldb, kd, 0, lds + NB1, t); }
  BARR;
  MM16(aF, bG, 0);
  if constexpr (!LAST) asm volatile("s_waitcnt vmcnt(3)" ::: "memory");
  BARR;

  if constexpr (!LAST) {
    RD_A4(aF, NA0, 0);
    RD_B4(bF, NB0);
    stage_h256(Ab, lda, kd, 1, lds + NA1, t);
    stage_h128(Bb, ldb, kd, 1, lds + NB1, t);
  }
  BARR;
  MM16(aG, bG, 1);
  BARR;
}

template<bool LAST>
__device__ __forceinline__ void pv_iterRA(const ushort_t* __restrict__ Ab,
                                          const ushort_t* __restrict__ Bb,
                                          ushort_t* lds, const float (*ScL)[256],
                                          f32x4 (&acc)[4][4],
                                          int ka, int t, int arow_l, int brow_l,
                                          int ck0, int ck1,
                                          f16x8 (&aF)[2][2], f16x8 (&aG)[2][2],
                                          f16x8 (&bF)[2][2][2], f16x8 (&bG)[2][2][2])
{
  const int kc = ka + 128, kd = ka + 192;
  const int cba = ka >> 6;
  float sa4[4], sb4[4];
#pragma unroll
  for (int s = 0; s < 4; ++s) {
    sa4[s] = ScL[cba][arow_l + s * 16];
    sb4[s] = ScL[cba + 1][arow_l + s * 16];
  }

  RD_A4(aG, NA0, 1);
  if constexpr (!LAST) { stage_h256(Ab, 2048, kc, 0, lds + NA0, t);
                         stage_h128(Bb, 2048, kc, 0, lds + NB0, t); }
  BARR;
  MM16S(aF, bF, 0, sa4);
  if constexpr (LAST) asm volatile("s_waitcnt vmcnt(0)" ::: "memory");
  else                asm volatile("s_waitcnt vmcnt(3)" ::: "memory");
  BARR;

  RD_A4(aF, NA1, 0);
  RD_B4(bG, NB1);
  if constexpr (!LAST) { stage_h256(Ab, 2048, kc, 1, lds + NA0, t);
                         stage_h128(Bb, 2048, kc, 1, lds + NB0, t); }
  BARR;
  MM16S(aG, bF, 1, sa4);
  BARR;

  RD_A4(aG, NA1, 1);
  if constexpr (!LAST) { stage_h256(Ab, 2048, kd, 0, lds + NA1, t);
                         stage_h128(Bb, 2048, kd, 0, lds + NB1, t); }
  BARR;
  MM16S(aF, bG, 0, sb4);
  if constexpr (!LAST) asm volatile("s_waitcnt vmcnt(3)" ::: "memory");
  BARR;

  if constexpr (!LAST) {
    RD_A4(aF, NA0, 0);
    RD_B4(bF, NB0);
    stage_h256(Ab, 2048, kd, 1, lds + NA1, t);
    stage_h128(Bb, 2048, kd, 1, lds + NB1, t);
  }
  BARR;
  MM16S(aG, bG, 1, sb4);
  BARR;
}

#define PROLOGUE_RA(LDA, LDB)                               \
  do {                                                      \
    stage_h256(Ab, (LDA),  0, 0, lds + NA0, t);             \
    stage_h128(Bb, (LDB),  0, 0, lds + NB0, t);             \
    stage_h256(Ab, (LDA),  0, 1, lds + NA0, t);             \
    stage_h128(Bb, (LDB),  0, 1, lds + NB0, t);             \
    asm volatile("s_waitcnt vmcnt(0)" ::: "memory");        \
    BARR;                                                   \
    RD_A4(aF, NA0, 0);                                      \
    RD_B4(bF, NB0);                                         \
    stage_h256(Ab, (LDA), 64, 0, lds + NA1, t);             \
    stage_h128(Bb, (LDB), 64, 0, lds + NB1, t);             \
    stage_h256(Ab, (LDA), 64, 1, lds + NA1, t);             \
    stage_h128(Bb, (LDB), 64, 1, lds + NB1, t);             \
    BARR;                                                   \
  } while (0)

// ---------------------------------------------------------------------------
// QK-projection on the 256x256 core. A = Xh [8192][1024], BT = Wt rows
// 0..2047 (Wq^T|Wk^T). grid (8, M/256) = 256 blocks = 1 round.
// Store via per-wave LDS slice -> coalesced f16x8 global stores.
// ---------------------------------------------------------------------------
__global__ __launch_bounds__(512, 2)
void qkproj_kernel(const ushort_t* __restrict__ A, const ushort_t* __restrict__ BT,
                   const float* __restrict__ bq, const float* __restrict__ bk,
                   __half* __restrict__ Qh, __half* __restrict__ Kh)
{
  __shared__ __align__(16) ushort_t lds[65536];   // 128 KB

  const int nb = gridDim.x * gridDim.y;           // 256, %8==0
  int id = blockIdx.y * gridDim.x + blockIdx.x;
  id = (id & 7) * (nb >> 3) + (id >> 3);          // bijective XCD swizzle
  const int bx = id % gridDim.x;                  // 0..7 (N-tile of 256 over Q|K)
  const int by = id / gridDim.x;                  // M-tile of 256

  const ushort_t* Ab = A  + (long)by * 256 * 1024;
  const ushort_t* Bb = BT + (long)bx * 256 * 1024;

  f32x4 acc[8][4];
  const f32x4 zero = {0.0f, 0.0f, 0.0f, 0.0f};
#pragma unroll
  for (int i = 0; i < 8; ++i)
#pragma unroll
    for (int j = 0; j < 4; ++j) acc[i][j] = zero;

  gemm256(Ab, Bb, lds, acc);

  const int t = threadIdx.x, lane = t & 63, wave = t >> 6;
  const int wr = wave >> 2, wc = wave & 3;
  const int er4 = (lane >> 4) * 4, ec = lane & 15;
  const int tgt = bx >> 2;                        // 0:Q 1:K (uniform)
  const float* bias = (tgt == 0) ? bq : bk;
  __half* o = (tgt == 0) ? Qh : Kh;

  float bv[4];
#pragma unroll
  for (int n4 = 0; n4 < 4; ++n4)
    bv[n4] = bias[(bx & 3) * 256 + wc * 64 + n4 * 16 + ec];

  _Float16* ws = (_Float16*)lds + wave * 4608;    // 64 x 72 halfs slice
  const long gr0 = (long)by * 256 + wr * 128;
  const int  gc0 = (bx & 3) * 256 + wc * 64;

#pragma unroll
  for (int h = 0; h < 2; ++h) {
    LGKM0;
#pragma unroll
    for (int m4 = 0; m4 < 4; ++m4)
#pragma unroll
      for (int n4 = 0; n4 < 4; ++n4)
#pragma unroll
        for (int r = 0; r < 4; ++r)
          ws[(m4 * 16 + er4 + r) * 72 + n4 * 16 + ec] =
              (_Float16)(acc[h * 4 + m4][n4][r] + bv[n4]);
    LGKM0;
#pragma unroll
    for (int p = 0; p < 8; ++p) {
      const int lrow = p * 8 + (lane >> 3);
      const int coff = (lane & 7) * 8;
      const f16x8 v = *(const f16x8*)&ws[lrow * 72 + coff];
      *(f16x8*)((_Float16*)o + (gr0 + h * 64 + lrow) * 1024 + gc0 + coff) = v;
    }
  }
}

// ---------------------------------------------------------------------------
// V-projection on the RA-128 core. BT rows 2048+bx*128. grid (8, M/256).
// Vt store via transposed [col][ml] LDS slice -> contiguous 128B per column.
// ---------------------------------------------------------------------------
__global__ __launch_bounds__(512, 2)
void vproj_kernel(const ushort_t* __restrict__ A, const ushort_t* __restrict__ BT,
                  const float* __restrict__ bvp, ushort_t* __restrict__ Vt)
{
  __shared__ __align__(16) ushort_t lds[49152];   // 96 KB

  const int nb = gridDim.x * gridDim.y;           // 256, %8==0
  int id = blockIdx.y * gridDim.x + blockIdx.x;
  id = (id & 7) * (nb >> 3) + (id >> 3);
  const int bx = id % gridDim.x;                  // 0..7 (V N-tile of 128)
  const int by = id / gridDim.x;                  // M-tile of 256

  const ushort_t* Ab = A  + (long)by * 256 * 1024;
  const ushort_t* Bb = BT + (long)(16 + bx) * 128 * 1024;

  const int t    = threadIdx.x;
  const int lane = t & 63;
  const int wave = t >> 6;
  const int wr   = wave >> 1;                     // 0..3
  const int wc   = wave & 1;                      // 0..1
  const int arow_l = wr * 64 + (lane & 15);
  const int brow_l = wc * 64 + (lane & 15);
  const int ck0 = (((lane >> 4)    ) ^ (lane & 7)) * 8;
  const int ck1 = ((4 + (lane >> 4)) ^ (lane & 7)) * 8;

  f32x4 acc[4][4];
  const f32x4 zero = {0.0f, 0.0f, 0.0f, 0.0f};
#pragma unroll
  for (int i = 0; i < 4; ++i)
#pragma unroll
    for (int j = 0; j < 4; ++j) acc[i][j] = zero;

  f16x8 aF[2][2], aG[2][2], bF[2][2][2], bG[2][2][2];

  PROLOGUE_RA(1024, 1024);
#pragma unroll 1
  for (int it = 0; it < 7; ++it)
    iterRA<false>(Ab, Bb, 1024, 1024, lds, acc, it * 128, t, arow_l, brow_l,
                  ck0, ck1, aF, aG, bF, bG);
  iterRA<true>(Ab, Bb, 1024, 1024, lds, acc, 896, t, arow_l, brow_l,
               ck0, ck1, aF, aG, bF, bG);

  const int er4 = (lane >> 4) * 4, ec = lane & 15;

  // transposed [col][ml] slice: 64 cols x 72-stride halfs per wave
  _Float16* ws = (_Float16*)lds + wave * 4608;
  LGKM0;
#pragma unroll
  for (int ni = 0; ni < 4; ++ni) {
    const float bval = bvp[bx * 128 + wc * 64 + ni * 16 + ec];
#pragma unroll
    for (int mi = 0; mi < 4; ++mi) {
      f16x4 v4;
#pragma unroll
      for (int r = 0; r < 4; ++r) v4[r] = (_Float16)(acc[mi][ni][r] + bval);
      *(f16x4*)&ws[(ni * 16 + ec) * 72 + mi * 16 + er4] = v4;
    }
  }
  LGKM0;
  const long b   = by >> 3;                        // batch (256 rows in one batch)
  const int  mlb = ((by * 256) & 2047) + wr * 64;  // ml base for this wave
#pragma unroll
  for (int p = 0; p < 8; ++p) {
    const int lcol = p * 8 + (lane >> 3);
    const int moff = (lane & 7) * 8;
    const f16x8 v = *(const f16x8*)&ws[lcol * 72 + moff];
    *(f16x8*)&Vt[b * 2097152 + (long)(bx * 128 + wc * 64 + lcol) * 2048 + mlb + moff] = v;
  }
}

// ---------------------------------------------------------------------------
// QK^T on the 256x256 core with fused partial softmax, 64-col chunks.
// Breadth-first shuffle reduction + LDS-staged coalesced S store.
// Wave (wr,wc) owns 128 rows x 64 cols; chunk cc = bx*4+wc. grid (8,8,4).
// ---------------------------------------------------------------------------
__global__ __launch_bounds__(512, 2)
void qkattn_kernel(const ushort_t* __restrict__ Q, const ushort_t* __restrict__ Kh,
                   __half* __restrict__ S, float* __restrict__ PM, float* __restrict__ PS)
{
  __shared__ __align__(16) ushort_t lds[65536];

  const int nb = gridDim.x * gridDim.y;           // 64, %8==0
  int id = blockIdx.y * gridDim.x + blockIdx.x;
  id = (id & 7) * (nb >> 3) + (id >> 3);
  const int bx = id % gridDim.x;                  // 0..7 (K-tile of 256)
  const int by = id / gridDim.x;                  // 0..7 (Q-tile of 256)
  const long z = blockIdx.z;

  const ushort_t* Ab = Q  + z * 2048 * 1024 + (long)by * 256 * 1024;
  const ushort_t* Bb = Kh + z * 2048 * 1024 + (long)bx * 256 * 1024;
  __half* Sb = S + z * 2048 * 2048;

  f32x4 acc[8][4];
  const f32x4 zero = {0.0f, 0.0f, 0.0f, 0.0f};
#pragma unroll
  for (int i = 0; i < 8; ++i)
#pragma unroll
    for (int j = 0; j < 4; ++j) acc[i][j] = zero;

  gemm256(Ab, Bb, lds, acc);

  const int t = threadIdx.x, lane = t & 63, wave = t >> 6;
  const int wr = wave >> 2, wc = wave & 3;
  const int er4 = (lane >> 4) * 4, ec = lane & 15;
  const int cc = bx * 4 + wc;                     // 0..31
  float* PMb = PM + z * 32 * 2048 + (long)cc * 2048;
  float* PSb = PS + z * 32 * 2048 + (long)cc * 2048;

  // ---- breadth-first softmax: 32 independent chains per shuffle step ----
  float mrow[32], srow[32];
#pragma unroll
  for (int m8 = 0; m8 < 8; ++m8)
#pragma unroll
    for (int r = 0; r < 4; ++r)
      mrow[m8 * 4 + r] = fmaxf(fmaxf(acc[m8][0][r], acc[m8][1][r]),
                               fmaxf(acc[m8][2][r], acc[m8][3][r]));
#pragma unroll
  for (int st = 1; st <= 8; st <<= 1)
#pragma unroll
    for (int i = 0; i < 32; ++i)
      mrow[i] = fmaxf(mrow[i], __shfl_xor(mrow[i], st));
#pragma unroll
  for (int m8 = 0; m8 < 8; ++m8)
#pragma unroll
    for (int r = 0; r < 4; ++r) {
      float s = 0.0f;
#pragma unroll
      for (int n4 = 0; n4 < 4; ++n4) {
        const float e = __expf(acc[m8][n4][r] - mrow[m8 * 4 + r]);
        acc[m8][n4][r] = e;
        s += e;
      }
      srow[m8 * 4 + r] = s;
    }
#pragma unroll
  for (int st = 1; st <= 8; st <<= 1)
#pragma unroll
    for (int i = 0; i < 32; ++i)
      srow[i] += __shfl_xor(srow[i], st);

  if (ec == 0) {
#pragma unroll
    for (int i = 0; i < 32; ++i) {
      const long row = (long)by * 256 + wr * 128 + (i >> 2) * 16 + er4 + (i & 3);
      PMb[row] = mrow[i];
      PSb[row] = srow[i];
    }
  }

  // ---- S store via per-wave LDS slice (two 64-row halves) ----
  _Float16* ws = (_Float16*)lds + wave * 4608;    // 64 x 72 halfs
  const long gr0 = (long)by * 256 + wr * 128;
  const int  gc0 = bx * 256 + wc * 64;
#pragma unroll
  for (int h = 0; h < 2; ++h) {
    LGKM0;
#pragma unroll
    for (int m4 = 0; m4 < 4; ++m4)
#pragma unroll
      for (int n4 = 0; n4 < 4; ++n4)
#pragma unroll
        for (int r = 0; r < 4; ++r)
          ws[(m4 * 16 + er4 + r) * 72 + n4 * 16 + ec] =
              (_Float16)acc[h * 4 + m4][n4][r];
    LGKM0;
#pragma unroll
    for (int p = 0; p < 8; ++p) {
      const int lrow = p * 8 + (lane >> 3);
      const int coff = (lane & 7) * 8;
      const f16x8 v = *(const f16x8*)&ws[lrow * 72 + coff];
      *(f16x8*)((_Float16*)Sb + (gr0 + h * 64 + lrow) * 2048 + gc0 + coff) = v;
    }
  }
}

// ---------------------------------------------------------------------------
// PV on the RA-128 core, softmax-reduce fused into the prologue.
// grid (8, 8, 4) = 256 blocks. K = 2048.
// ---------------------------------------------------------------------------
__global__ __launch_bounds__(512, 2)
void pv_ra_kernel(const ushort_t* __restrict__ S, const ushort_t* __restrict__ Vt,
                  const float* __restrict__ PM, const float* __restrict__ PS,
                  float* __restrict__ Out)
{
  __shared__ __align__(16) ushort_t lds[49152];   // 96 KB
  __shared__ float ScL[32][256];                  // +32 KB = 128 KB

  const int nb = gridDim.x * gridDim.y;           // 64, %8==0
  int id = blockIdx.y * gridDim.x + blockIdx.x;
  id = (id & 7) * (nb >> 3) + (id >> 3);
  const int bx = id % gridDim.x;                  // N-tile (Out cols / Vt rows)
  const int by = id / gridDim.x;                  // M-tile (S rows)
  const long z = blockIdx.z;

  const ushort_t* Ab = S  + z * 4194304 + (long)by * 256 * 2048;
  const ushort_t* Bb = Vt + z * 2097152 + (long)bx * 128 * 2048;
  float* Cb = Out + z * 2048 * 1024;

  const int t = threadIdx.x;

  // ---- fused softmax reduce for this block's 256 rows ----
  if (t < 256) {
    const long row = (long)by * 256 + t;
    const float* PMb = PM + z * 32 * 2048;
    const float* PSb = PS + z * 32 * 2048;
    float pm[32];
    float m = -3.4e38f;
#pragma unroll
    for (int cb = 0; cb < 32; ++cb) {
      pm[cb] = PMb[(long)cb * 2048 + row];
      m = fmaxf(m, pm[cb]);
    }
    float l = 0.0f;
#pragma unroll
    for (int cb = 0; cb < 32; ++cb)
      l += PSb[(long)cb * 2048 + row] * __expf(pm[cb] - m);
    const float inv = 1.0f / l;
#pragma unroll
    for (int cb = 0; cb < 32; ++cb)
      ScL[cb][t] = __expf(pm[cb] - m) * inv;
  }
  __syncthreads();   // full drain; ScL visible; vmcnt clean before staging

  const int lane = t & 63;
  const int wave = t >> 6;
  const int wr   = wave >> 1;
  const int wc   = wave & 1;
  const int arow_l = wr * 64 + (lane & 15);
  const int brow_l = wc * 64 + (lane & 15);
  const int ck0 = (((lane >> 4)    ) ^ (lane & 7)) * 8;
  const int ck1 = ((4 + (lane >> 4)) ^ (lane & 7)) * 8;

  f32x4 acc[4][4];
  const f32x4 zero = {0.0f, 0.0f, 0.0f, 0.0f};
#pragma unroll
  for (int i = 0; i < 4; ++i)
#pragma unroll
    for (int j = 0; j < 4; ++j) acc[i][j] = zero;

  f16x8 aF[2][2], aG[2][2], bF[2][2][2], bG[2][2][2];

  PROLOGUE_RA(2048, 2048);
#pragma unroll 1
  for (int it = 0; it < 15; ++it)
    pv_iterRA<false>(Ab, Bb, lds, ScL, acc, it * 128, t, arow_l, brow_l,
                     ck0, ck1, aF, aG, bF, bG);
  pv_iterRA<true>(Ab, Bb, lds, ScL, acc, 1920, t, arow_l, brow_l,
                  ck0, ck1, aF, aG, bF, bG);

  const int er4 = (lane >> 4) * 4, ec = lane & 15;
#pragma unroll
  for (int ni = 0; ni < 4; ++ni) {
    const int gcol = bx * 128 + wc * 64 + ni * 16 + ec;
#pragma unroll
    for (int mi = 0; mi < 4; ++mi) {
#pragma unroll
      for (int r = 0; r < 4; ++r) {
        const long grow = (long)by * 256 + wr * 64 + mi * 16 + er4 + r;
        Cb[grow * 1024 + gcol] = acc[mi][ni][r];
      }
    }
  }
}

// ---------------------------------------------------------------------------
// Fused prep: z<3 -> weight transpose+cvt; z>=3 -> X fp32->fp16 slice.
// grid (32, 32, 7), 256 thr.
// ---------------------------------------------------------------------------
__global__ __launch_bounds__(256)
void prep_kernel(const float* __restrict__ W0, const float* __restrict__ W1,
                 const float* __restrict__ W2, __half* __restrict__ dstW,
                 const float* __restrict__ X, __half* __restrict__ Xh)
{
  __shared__ float tile[32][33];
  const int z = blockIdx.z;
  if (z < 3) {
    const float* src = (z == 0) ? W0 : (z == 1) ? W1 : W2;
    __half* d = dstW + (long)z * 1024 * 1024;
    const int c0 = blockIdx.x * 32;
    const int r0 = blockIdx.y * 32;
    const int tx = threadIdx.x & 31;
    const int ty = threadIdx.x >> 5;
#pragma unroll
    for (int i = 0; i < 32; i += 8)
      tile[ty + i][tx] = src[(long)(r0 + ty + i) * 1024 + (c0 + tx)];
    __syncthreads();
#pragma unroll
    for (int i = 0; i < 32; i += 8)
      d[(long)(c0 + ty + i) * 1024 + (r0 + tx)] = __float2half(tile[tx][ty + i]);
  } else {
    const int bid = blockIdx.y * gridDim.x + blockIdx.x;        // 0..1023
    const long i = (((long)(z - 3) * 1024 + bid) * 256 + threadIdx.x) * 8;
    const float4 a = *(const float4*)(X + i);
    const float4 b = *(const float4*)(X + i + 4);
    f16x8 h;
    h[0] = (_Float16)a.x; h[1] = (_Float16)a.y; h[2] = (_Float16)a.z; h[3] = (_Float16)a.w;
    h[4] = (_Float16)b.x; h[5] = (_Float16)b.y; h[6] = (_Float16)b.z; h[7] = (_Float16)b.w;
    *(f16x8*)((ushort_t*)Xh + i) = h;
  }
}

// ---------------------------------------------------------------------------
extern "C" void kernel_launch(void* const* d_in, const int* in_sizes, int n_in,
                              void* d_out, int out_size, void* d_ws, size_t ws_size,
                              hipStream_t stream)
{
  const int  Bb = 4, Nn = 2048, Dd = 1024;
  const long BN = (long)Bb * Nn;  // 8192

  const float* X  = (const float*)d_in[0];
  const float* Wq = (const float*)d_in[1];
  const float* bq = (const float*)d_in[2];
  const float* Wk = (const float*)d_in[3];
  const float* bk = (const float*)d_in[4];
  const float* Wv = (const float*)d_in[5];
  const float* bv = (const float*)d_in[6];
  float* Out      = (float*)d_out;

  uint8_t* w = (uint8_t*)d_ws;
  ushort_t* Wt = (ushort_t*)w;  w += (size_t)3 * Dd * Dd * 2;  // Wq^T|Wk^T|Wv^T fp16

  const size_t statsBytes = (size_t)Bb * 32 * Nn * 4;   // 1 MB each
  const size_t fullNeed = (size_t)3 * Dd * Dd * 2       // Wt
                        + 4 * ((size_t)BN * Dd * 2)     // Xh, Q, K, Vt fp16
                        + (size_t)Bb * Nn * Nn * 2      // S fp16
                        + 2 * statsBytes;               // PM, PS

  if (ws_size >= fullNeed) {
    ushort_t* Xh = (ushort_t*)w;  w += (size_t)BN * Dd * 2;
    ushort_t* Q  = (ushort_t*)w;  w += (size_t)BN * Dd * 2;
    ushort_t* Kb = (ushort_t*)w;  w += (size_t)BN * Dd * 2;
    ushort_t* Vt = (ushort_t*)w;  w += (size_t)BN * Dd * 2;  // [B][Dd][Nn]
    ushort_t* S  = (ushort_t*)w;  w += (size_t)Bb * Nn * Nn * 2;
    float*    PM = (float*)w;     w += statsBytes;
    float*    PS = (float*)w;

    prep_kernel<<<dim3(32, 32, 7), 256, 0, stream>>>(Wq, Wk, Wv, (__half*)Wt, X, (__half*)Xh);

    vproj_kernel<<<dim3(8, BN / 256, 1), 512, 0, stream>>>(Xh, Wt, bv, Vt);

    qkproj_kernel<<<dim3(8, BN / 256, 1), 512, 0, stream>>>(
        Xh, Wt, bq, bk, (__half*)Q, (__half*)Kb);

    qkattn_kernel<<<dim3(Nn / 256, Nn / 256, Bb), 512, 0, stream>>>(
        Q, Kb, (__half*)S, PM, PS);

    pv_ra_kernel<<<dim3(Dd / 128, Nn / 256, Bb), 512, 0, stream>>>(
        S, Vt, PM, PS, Out);
  } else {
    // Per-batch fallback (~32 MB ws): same cores, z-extent 1
    ushort_t* Xh = (ushort_t*)w;  w += (size_t)Nn * Dd * 2;
    ushort_t* Q  = (ushort_t*)w;  w += (size_t)Nn * Dd * 2;
    ushort_t* Kb = (ushort_t*)w;  w += (size_t)Nn * Dd * 2;
    ushort_t* Vt = (ushort_t*)w;  w += (size_t)Nn * Dd * 2;
    ushort_t* S  = (ushort_t*)w;  w += (size_t)Nn * Nn * 2;
    float*    PM = (float*)w;     w += (size_t)32 * Nn * 4;
    float*    PS = (float*)w;

    for (int b = 0; b < Bb; ++b) {
      const float* Xb = X + (long)b * Nn * Dd;
      prep_kernel<<<dim3(32, 32, b == 0 ? 4 : 1), 256, 0, stream>>>(
          Wq, Wk, Wv, (__half*)Wt, Xb, (__half*)Xh);  // z=3 slice converts Xb
      vproj_kernel<<<dim3(8, Nn / 256, 1), 512, 0, stream>>>(Xh, Wt, bv, Vt);
      qkproj_kernel<<<dim3(8, Nn / 256, 1), 512, 0, stream>>>(
          Xh, Wt, bq, bk, (__half*)Q, (__half*)Kb);
      qkattn_kernel<<<dim3(Nn / 256, Nn / 256, 1), 512, 0, stream>>>(
          Q, Kb, (__half*)S, PM, PS);
      pv_ra_kernel<<<dim3(Dd / 128, Nn / 256, 1), 512, 0, stream>>>(
          S, Vt, PM, PS, Out + (long)b * Nn * Dd);
    }
  }
}